// Round 1
// baseline (363.325 us; speedup 1.0000x reference)
//
#include <hip/hip_runtime.h>
#include <math.h>

// FusedAttentionWithRPB: causal attention + bucketed 3D relative-position bias.
// B=4 H=8 S=1024 D=64, fp32. Baseline flash-style SIMT kernel (no MFMA yet).

constexpr int Bc = 4, Hc = 8, Sc = 1024, Dc = 64;
constexpr int QT = 64;   // q rows per block
constexpr int KT = 16;   // k rows per LDS tile
constexpr int NTHREADS = 256;

__global__ __launch_bounds__(NTHREADS) void attn_rpb_kernel(
    const float* __restrict__ q, const float* __restrict__ k, const float* __restrict__ v,
    const int* __restrict__ px, const int* __restrict__ py, const int* __restrict__ pz,
    const float* __restrict__ bx, const float* __restrict__ by, const float* __restrict__ bz,
    float* __restrict__ out)
{
    const int nq = Sc / QT;              // 16 q-tiles per (b,h)
    int bid = blockIdx.x;
    int qi = bid % nq;
    int bh = bid / nq;
    int h  = bh % Hc;
    int b  = bh / Hc;

    int t = threadIdx.x;                 // 0..255
    int r = t >> 2;                      // q-row within tile, 0..63
    int p = t & 3;                       // D-slice 0..3 (16 floats each)
    int qrow = qi * QT + r;

    __shared__ float Ks[KT * Dc];
    __shared__ float Vs[KT * Dc];
    __shared__ int kpx[KT], kpy[KT], kpz[KT];

    const size_t bhOff = ((size_t)(b * Hc + h)) * Sc;

    // Q slice -> registers (float4 x4 = 16 floats)
    float4 qv[4];
    {
        const float4* qp = (const float4*)(q + (bhOff + qrow) * (size_t)Dc + p * 16);
        qv[0] = qp[0]; qv[1] = qp[1]; qv[2] = qp[2]; qv[3] = qp[3];
    }
    const int qpx = px[b * Sc + qrow];
    const int qpy = py[b * Sc + qrow];
    const int qpz = pz[b * Sc + qrow];

    float m = -INFINITY, l = 0.0f;
    float4 o[4];
    #pragma unroll
    for (int i = 0; i < 4; ++i) o[i] = make_float4(0.f, 0.f, 0.f, 0.f);

    const int ntiles = (qi + 1) * (QT / KT);   // causal: keys < (qi+1)*64

    for (int kt = 0; kt < ntiles; ++kt) {
        const int k0 = kt * KT;
        __syncthreads();
        // stage K/V tile: 16x64 floats = 256 float4 each; one float4 per thread
        {
            const float4* ksrc = (const float4*)(k + (bhOff + k0) * (size_t)Dc);
            const float4* vsrc = (const float4*)(v + (bhOff + k0) * (size_t)Dc);
            ((float4*)Ks)[t] = ksrc[t];
            ((float4*)Vs)[t] = vsrc[t];
            if (t < KT)            kpx[t]          = px[b * Sc + k0 + t];
            else if (t < 2 * KT)   kpy[t - KT]     = py[b * Sc + k0 + (t - KT)];
            else if (t < 3 * KT)   kpz[t - 2 * KT] = pz[b * Sc + k0 + (t - 2 * KT)];
        }
        __syncthreads();

        // scores for this thread's row, 16 keys
        float s[KT];
        #pragma unroll
        for (int j = 0; j < KT; ++j) {
            const float4* kr = (const float4*)(Ks + j * Dc + p * 16);
            float4 a0 = kr[0], a1 = kr[1], a2 = kr[2], a3 = kr[3];
            float acc;
            acc  = qv[0].x * a0.x + qv[0].y * a0.y + qv[0].z * a0.z + qv[0].w * a0.w;
            acc += qv[1].x * a1.x + qv[1].y * a1.y + qv[1].z * a1.z + qv[1].w * a1.w;
            acc += qv[2].x * a2.x + qv[2].y * a2.y + qv[2].z * a2.z + qv[2].w * a2.w;
            acc += qv[3].x * a3.x + qv[3].y * a3.y + qv[3].z * a3.z + qv[3].w * a3.w;
            // reduce across the 4 slice-threads (lanes differing in bits 0..1)
            acc += __shfl_xor(acc, 1);
            acc += __shfl_xor(acc, 2);
            acc *= 0.125f;   // 1/sqrt(64)
            // bucketed relative-position bias
            int dx = qpx - kpx[j]; dx = dx < -30 ? -30 : (dx > 30 ? 30 : dx);
            int dy = qpy - kpy[j]; dy = dy < -30 ? -30 : (dy > 30 ? 30 : dy);
            int dz = qpz - kpz[j]; dz = dz < -10 ? -10 : (dz > 10 ? 10 : dz);
            acc += bx[(dx + 30) * Hc + h] + by[(dy + 30) * Hc + h] + bz[(dz + 10) * Hc + h];
            const int kg = k0 + j;
            s[j] = (kg <= qrow) ? acc : -INFINITY;
        }

        // online softmax update
        float cm = s[0];
        #pragma unroll
        for (int j = 1; j < KT; ++j) cm = fmaxf(cm, s[j]);
        const float mn = fmaxf(m, cm);
        const float alpha = __expf(m - mn);   // m=-inf on first tile -> 0
        float pj[KT];
        float psum = 0.0f;
        #pragma unroll
        for (int j = 0; j < KT; ++j) { pj[j] = __expf(s[j] - mn); psum += pj[j]; }
        l = l * alpha + psum;
        m = mn;
        #pragma unroll
        for (int i = 0; i < 4; ++i) {
            o[i].x *= alpha; o[i].y *= alpha; o[i].z *= alpha; o[i].w *= alpha;
        }
        // o += p * V
        #pragma unroll
        for (int j = 0; j < KT; ++j) {
            const float4* vr = (const float4*)(Vs + j * Dc + p * 16);
            const float pw = pj[j];
            #pragma unroll
            for (int i = 0; i < 4; ++i) {
                float4 vv = vr[i];
                o[i].x += pw * vv.x; o[i].y += pw * vv.y;
                o[i].z += pw * vv.z; o[i].w += pw * vv.w;
            }
        }
    }

    const float inv = 1.0f / l;
    float4* op = (float4*)(out + (bhOff + qrow) * (size_t)Dc + p * 16);
    #pragma unroll
    for (int i = 0; i < 4; ++i)
        op[i] = make_float4(o[i].x * inv, o[i].y * inv, o[i].z * inv, o[i].w * inv);
}

extern "C" void kernel_launch(void* const* d_in, const int* in_sizes, int n_in,
                              void* d_out, int out_size, void* d_ws, size_t ws_size,
                              hipStream_t stream) {
    const float* q  = (const float*)d_in[0];
    const float* k  = (const float*)d_in[1];
    const float* v  = (const float*)d_in[2];
    const int*   px = (const int*)d_in[3];
    const int*   py = (const int*)d_in[4];
    const int*   pz = (const int*)d_in[5];
    const float* bx = (const float*)d_in[6];
    const float* by = (const float*)d_in[7];
    const float* bz = (const float*)d_in[8];
    float* out = (float*)d_out;

    const int grid = (Sc / QT) * Bc * Hc;   // 16 * 32 = 512 blocks
    attn_rpb_kernel<<<grid, NTHREADS, 0, stream>>>(q, k, v, px, py, pz, bx, by, bz, out);
}

// Round 2
// 60.234 us; speedup vs baseline: 6.0319x; 6.0319x over previous
//
#include <hip/hip_runtime.h>
#include <math.h>

// FusedAttentionWithRPB: causal attention + bucketed 3D relative-position bias.
// B=4 H=8 S=1024 D=64, fp32 I/O. MFMA bf16 flash kernel.
// Block = one (b,h,qtile of 64 rows), 256 threads = 4 waves, each wave a 16-row strip.

constexpr int Bc = 4, Hc = 8, Sc = 1024, Dc = 64;
constexpr int NTHREADS = 256;

typedef __attribute__((ext_vector_type(8))) short bf16x8;
typedef __attribute__((ext_vector_type(4))) float f32x4;

__device__ __forceinline__ unsigned short f2bf(float f) {
  union { float f; unsigned u; } x; x.f = f;
  unsigned r = x.u + 0x7FFFu + ((x.u >> 16) & 1u);
  return (unsigned short)(r >> 16);
}

__device__ __forceinline__ bf16x8 pack8(float4 a, float4 b) {
  bf16x8 r;
  r[0] = (short)f2bf(a.x); r[1] = (short)f2bf(a.y);
  r[2] = (short)f2bf(a.z); r[3] = (short)f2bf(a.w);
  r[4] = (short)f2bf(b.x); r[5] = (short)f2bf(b.y);
  r[6] = (short)f2bf(b.z); r[7] = (short)f2bf(b.w);
  return r;
}

// swizzled byte offset inside a 64x64 bf16 tile (row pitch 128B).
// XOR of row bits into the 16B-slot bits kills the 16-way ds_read_b128 conflict.
__device__ __forceinline__ int swzb(int row, int col) {
  return ((row << 7) + (col << 1)) ^ ((row & 7) << 4);
}

__global__ __launch_bounds__(NTHREADS) void attn_rpb_mfma(
    const float* __restrict__ qg, const float* __restrict__ kg, const float* __restrict__ vg,
    const int* __restrict__ px, const int* __restrict__ py, const int* __restrict__ pz,
    const float* __restrict__ bx, const float* __restrict__ by, const float* __restrict__ bz,
    float* __restrict__ outg)
{
  // Balanced causal mapping: blocks j and j+256 get complementary q-tiles
  // (qi and 15-qi), so each CU's two resident blocks sum to constant work.
  const int j   = blockIdx.x;
  const int idx = j & 255;
  const int bh  = idx >> 3;
  const int r3  = idx & 7;
  const int qi  = (j < 256) ? (15 - r3) : r3;
  const int h = bh & 7, b = bh >> 3;

  __shared__ unsigned short Qs[64 * 64];   // bf16, swizzled
  __shared__ unsigned short Kb[64 * 64];   // bf16, swizzled
  __shared__ unsigned short Ps[64 * 64];   // bf16, swizzled (wave-private rows)
  __shared__ unsigned short Vt[64 * 72];   // bf16, transposed [d][key], padded pitch
  __shared__ float bxh[61], byh[61], bzh[21];
  __shared__ int qxs[64], qys[64], qzs[64];
  __shared__ int kxs[64], kys[64], kzs[64];

  const int t  = threadIdx.x;
  const int w  = t >> 6;          // wave 0..3 -> rows [16w, 16w+16)
  const int l  = t & 63;
  const int lg = l >> 4;          // lane group 0..3
  const int lr = l & 15;          // lane-in-group 0..15
  const size_t bhOff = (size_t)(b * Hc + h) * Sc;
  const int q0 = qi * 64;

  // ---- one-time staging: Q tile, q positions, per-head bias rows
  {
    const int row = t >> 2, c0 = (t & 3) * 16;
    const float4* src = (const float4*)(qg + (bhOff + q0 + row) * Dc + c0);
    float4 a0 = src[0], a1 = src[1], a2 = src[2], a3 = src[3];
    *(bf16x8*)((char*)Qs + swzb(row, c0))     = pack8(a0, a1);
    *(bf16x8*)((char*)Qs + swzb(row, c0 + 8)) = pack8(a2, a3);
  }
  if (t < 64) { qxs[t] = px[b*Sc + q0 + t]; qys[t] = py[b*Sc + q0 + t]; qzs[t] = pz[b*Sc + q0 + t]; }
  if (t < 61)              bxh[t]       = bx[t * Hc + h];
  if (t >= 64 && t < 125)  byh[t - 64]  = by[(t - 64) * Hc + h];
  if (t >= 128 && t < 149) bzh[t - 128] = bz[(t - 128) * Hc + h];
  __syncthreads();

  // Q fragments stay in registers for the whole K loop
  bf16x8 aq[2];
  aq[0] = *(const bf16x8*)((const char*)Qs + swzb(16 * w + lr, 8 * lg));
  aq[1] = *(const bf16x8*)((const char*)Qs + swzb(16 * w + lr, 8 * lg + 32));

  int rowg[4], qxv[4], qyv[4], qzv[4];
  #pragma unroll
  for (int r = 0; r < 4; ++r) {
    const int rl = 16 * w + 4 * lg + r;   // D-layout row for acc reg r
    rowg[r] = q0 + rl;
    qxv[r] = qxs[rl]; qyv[r] = qys[rl]; qzv[r] = qzs[rl];
  }

  float mrow[4], lsum[4];
  f32x4 O[4];
  const f32x4 zero4 = {0.f, 0.f, 0.f, 0.f};
  #pragma unroll
  for (int r = 0; r < 4; ++r) { mrow[r] = -INFINITY; lsum[r] = 0.f; }
  #pragma unroll
  for (int nt = 0; nt < 4; ++nt) O[nt] = zero4;

  const int ntl = qi + 1;   // causal: 64-key tiles
  for (int kt = 0; kt < ntl; ++kt) {
    const int k0 = kt * 64;
    __syncthreads();   // previous iteration's Kb/Vt reads complete
    {
      const int row = t >> 2, c0 = (t & 3) * 16;
      const float4* ks_ = (const float4*)(kg + (bhOff + k0 + row) * Dc + c0);
      float4 a0 = ks_[0], a1 = ks_[1], a2 = ks_[2], a3 = ks_[3];
      *(bf16x8*)((char*)Kb + swzb(row, c0))     = pack8(a0, a1);
      *(bf16x8*)((char*)Kb + swzb(row, c0 + 8)) = pack8(a2, a3);
      const float4* vs_ = (const float4*)(vg + (bhOff + k0 + row) * Dc + c0);
      float tv[16];
      *(float4*)(tv)      = vs_[0]; *(float4*)(tv + 4)  = vs_[1];
      *(float4*)(tv + 8)  = vs_[2]; *(float4*)(tv + 12) = vs_[3];
      #pragma unroll
      for (int i = 0; i < 16; ++i) Vt[(c0 + i) * 72 + row] = f2bf(tv[i]);
    }
    if (t < 64)       kxs[t]       = px[b*Sc + k0 + t];
    else if (t < 128) kys[t - 64]  = py[b*Sc + k0 + (t - 64)];
    else if (t < 192) kzs[t - 128] = pz[b*Sc + k0 + (t - 128)];
    __syncthreads();

    // ---- S = Q K^T : A-frag = Q rows, B-frag = K rows (B = K^T)
    f32x4 s[4];
    #pragma unroll
    for (int ct = 0; ct < 4; ++ct) {
      s[ct] = zero4;
      #pragma unroll
      for (int ks = 0; ks < 2; ++ks) {
        bf16x8 bk = *(const bf16x8*)((const char*)Kb + swzb(16*ct + lr, 8*lg + 32*ks));
        s[ct] = __builtin_amdgcn_mfma_f32_16x16x32_bf16(aq[ks], bk, s[ct], 0, 0, 0);
      }
    }

    // ---- scale + 3D bucketed bias + causal mask (diagonal tile only)
    const bool diag = (kt == qi);
    #pragma unroll
    for (int ct = 0; ct < 4; ++ct) {
      const int colg = k0 + 16*ct + lr;
      const int kxv = kxs[16*ct + lr], kyv = kys[16*ct + lr], kzv = kzs[16*ct + lr];
      #pragma unroll
      for (int r = 0; r < 4; ++r) {
        float val = s[ct][r] * 0.125f;   // 1/sqrt(64)
        int dx = qxv[r] - kxv; dx = dx < -30 ? -30 : (dx > 30 ? 30 : dx);
        int dy = qyv[r] - kyv; dy = dy < -30 ? -30 : (dy > 30 ? 30 : dy);
        int dz = qzv[r] - kzv; dz = dz < -10 ? -10 : (dz > 10 ? 10 : dz);
        val += bxh[dx + 30] + byh[dy + 30] + bzh[dz + 10];
        if (diag && colg > rowg[r]) val = -INFINITY;
        s[ct][r] = val;
      }
    }

    // ---- online softmax (row = (reg, lane-group); cols across 16 lanes x 4 ct)
    float rmax[4];
    #pragma unroll
    for (int r = 0; r < 4; ++r)
      rmax[r] = fmaxf(fmaxf(s[0][r], s[1][r]), fmaxf(s[2][r], s[3][r]));
    #pragma unroll
    for (int mask = 1; mask <= 8; mask <<= 1) {
      #pragma unroll
      for (int r = 0; r < 4; ++r)
        rmax[r] = fmaxf(rmax[r], __shfl_xor(rmax[r], mask));
    }
    float alpha[4], psum[4];
    #pragma unroll
    for (int r = 0; r < 4; ++r) {
      const float mn = fmaxf(mrow[r], rmax[r]);
      alpha[r] = __expf(mrow[r] - mn);   // first tile: exp(-inf)=0
      mrow[r] = mn;
      psum[r] = 0.f;
    }
    #pragma unroll
    for (int ct = 0; ct < 4; ++ct) {
      #pragma unroll
      for (int r = 0; r < 4; ++r) {
        const float p = __expf(s[ct][r] - mrow[r]);
        s[ct][r] = p;
        psum[r] += p;
      }
    }
    #pragma unroll
    for (int mask = 1; mask <= 8; mask <<= 1) {
      #pragma unroll
      for (int r = 0; r < 4; ++r)
        psum[r] += __shfl_xor(psum[r], mask);
    }
    #pragma unroll
    for (int r = 0; r < 4; ++r) lsum[r] = lsum[r] * alpha[r] + psum[r];
    #pragma unroll
    for (int nt = 0; nt < 4; ++nt) {
      #pragma unroll
      for (int r = 0; r < 4; ++r) O[nt][r] *= alpha[r];
    }

    // ---- P -> bf16 -> LDS (this wave's 16 rows only; no barrier needed)
    #pragma unroll
    for (int ct = 0; ct < 4; ++ct) {
      #pragma unroll
      for (int r = 0; r < 4; ++r)
        *(unsigned short*)((char*)Ps + swzb(16*w + 4*lg + r, 16*ct + lr)) = f2bf(s[ct][r]);
    }

    // ---- O += P V : A-frag = P rows (own wave), B-frag = Vt columns
    bf16x8 pa[2];
    pa[0] = *(const bf16x8*)((const char*)Ps + swzb(16*w + lr, 8*lg));
    pa[1] = *(const bf16x8*)((const char*)Ps + swzb(16*w + lr, 8*lg + 32));
    #pragma unroll
    for (int nt = 0; nt < 4; ++nt) {
      #pragma unroll
      for (int ks = 0; ks < 2; ++ks) {
        bf16x8 bv = *(const bf16x8*)((const unsigned short*)Vt + (16*nt + lr) * 72 + 8*lg + 32*ks);
        O[nt] = __builtin_amdgcn_mfma_f32_16x16x32_bf16(pa[ks], bv, O[nt], 0, 0, 0);
      }
    }
  }

  // ---- epilogue: normalize, store fp32
  #pragma unroll
  for (int r = 0; r < 4; ++r) {
    const float inv = 1.0f / lsum[r];
    #pragma unroll
    for (int nt = 0; nt < 4; ++nt)
      outg[(bhOff + q0 + 16*w + 4*lg + r) * Dc + 16*nt + lr] = O[nt][r] * inv;
  }
}

extern "C" void kernel_launch(void* const* d_in, const int* in_sizes, int n_in,
                              void* d_out, int out_size, void* d_ws, size_t ws_size,
                              hipStream_t stream) {
  const float* q  = (const float*)d_in[0];
  const float* k  = (const float*)d_in[1];
  const float* v  = (const float*)d_in[2];
  const int*   px = (const int*)d_in[3];
  const int*   py = (const int*)d_in[4];
  const int*   pz = (const int*)d_in[5];
  const float* bx = (const float*)d_in[6];
  const float* by = (const float*)d_in[7];
  const float* bz = (const float*)d_in[8];
  float* out = (float*)d_out;

  const int grid = (Sc / 64) * Bc * Hc;   // 512 blocks
  attn_rpb_mfma<<<grid, NTHREADS, 0, stream>>>(q, k, v, px, py, pz, bx, by, bz, out);
}

// Round 4
// 49.014 us; speedup vs baseline: 7.4127x; 1.2289x over previous
//
#include <hip/hip_runtime.h>
#include <math.h>

// FusedAttentionWithRPB: causal attention + bucketed 3D relative-position bias.
// B=4 H=8 S=1024 D=64, fp32 I/O. MFMA bf16 flash kernel, round 4:
//  - round-2 compute path (known good) incl. scalar Vt transpose staging
//  - double-buffered K/V/pos, prefetch-early / LDS-write-late (T14)
//  - ONE barrier per K-step (write->read of same buffer spans the barrier)
//  - 1/sqrt(D) folded into Q staging

constexpr int Bc = 4, Hc = 8, Sc = 1024, Dc = 64;
constexpr int NTHREADS = 256;

typedef __attribute__((ext_vector_type(8))) short bf16x8;
typedef __attribute__((ext_vector_type(4))) float f32x4;

__device__ __forceinline__ unsigned short f2bf(float f) {
  union { float f; unsigned u; } x; x.f = f;
  unsigned r = x.u + 0x7FFFu + ((x.u >> 16) & 1u);
  return (unsigned short)(r >> 16);
}

__device__ __forceinline__ bf16x8 pack8(float4 a, float4 b) {
  bf16x8 r;
  r[0] = (short)f2bf(a.x); r[1] = (short)f2bf(a.y);
  r[2] = (short)f2bf(a.z); r[3] = (short)f2bf(a.w);
  r[4] = (short)f2bf(b.x); r[5] = (short)f2bf(b.y);
  r[6] = (short)f2bf(b.z); r[7] = (short)f2bf(b.w);
  return r;
}

__device__ __forceinline__ float4 sc4(float4 a, float s) {
  return make_float4(a.x * s, a.y * s, a.z * s, a.w * s);
}

// swizzled byte offset inside a 64x64 bf16 tile (row pitch 128B): kills the
// 16-way ds_read_b128 conflict on column-slice reads.
__device__ __forceinline__ int swzb(int row, int col) {
  return ((row << 7) + (col << 1)) ^ ((row & 7) << 4);
}

__global__ __launch_bounds__(NTHREADS) void attn_rpb_mfma3(
    const float* __restrict__ qg, const float* __restrict__ kg, const float* __restrict__ vg,
    const int* __restrict__ px, const int* __restrict__ py, const int* __restrict__ pz,
    const float* __restrict__ bx, const float* __restrict__ by, const float* __restrict__ bz,
    float* __restrict__ outg)
{
  // Balanced causal mapping: blocks j and j+256 get complementary q-tiles.
  const int j   = blockIdx.x;
  const int idx = j & 255;
  const int bh  = idx >> 3;
  const int r3  = idx & 7;
  const int qi  = (j < 256) ? (15 - r3) : r3;
  const int h = bh & 7, b = bh >> 3;

  __shared__ unsigned short Qs[64 * 64];      // bf16, swizzled
  __shared__ unsigned short Kb[2][64 * 64];   // bf16, swizzled, double-buffered
  __shared__ unsigned short Vt[2][64 * 72];   // bf16, transposed [d][key], padded pitch
  __shared__ unsigned short Ps[64 * 64];      // bf16, swizzled (wave-private rows)
  __shared__ float bxh[61], byh[61], bzh[21];
  __shared__ int qxs[64], qys[64], qzs[64];
  __shared__ int kxs[2][64], kys[2][64], kzs[2][64];

  const int t  = threadIdx.x;
  const int w  = t >> 6;          // wave 0..3 -> q rows [16w, 16w+16)
  const int l  = t & 63;
  const int lg = l >> 4;          // lane group 0..3
  const int lr = l & 15;          // lane-in-group 0..15
  const size_t bhOff = (size_t)(b * Hc + h) * Sc;
  const int q0 = qi * 64;
  const int row = t >> 2, c0 = (t & 3) * 16;  // staging assignment

  // ---- prologue: tile-0 K/V/pos -> regs; Q (scaled) + tables -> LDS
  float4 ka0, ka1, ka2, ka3, va0, va1, va2, va3;
  int rp = 0;
  {
    const float4* kp = (const float4*)(kg + (bhOff + row) * Dc + c0);
    ka0 = kp[0]; ka1 = kp[1]; ka2 = kp[2]; ka3 = kp[3];
    const float4* vp = (const float4*)(vg + (bhOff + row) * Dc + c0);
    va0 = vp[0]; va1 = vp[1]; va2 = vp[2]; va3 = vp[3];
    if (t < 64)       rp = px[b * Sc + t];
    else if (t < 128) rp = py[b * Sc + (t - 64)];
    else if (t < 192) rp = pz[b * Sc + (t - 128)];
  }
  {
    const float4* qp = (const float4*)(qg + (bhOff + q0 + row) * Dc + c0);
    float4 a0 = sc4(qp[0], 0.125f), a1 = sc4(qp[1], 0.125f);
    float4 a2 = sc4(qp[2], 0.125f), a3 = sc4(qp[3], 0.125f);
    *(bf16x8*)((char*)Qs + swzb(row, c0))     = pack8(a0, a1);
    *(bf16x8*)((char*)Qs + swzb(row, c0 + 8)) = pack8(a2, a3);
  }
  if (t < 64) { qxs[t] = px[b*Sc + q0 + t]; qys[t] = py[b*Sc + q0 + t]; qzs[t] = pz[b*Sc + q0 + t]; }
  if (t < 61)                   bxh[t]       = bx[t * Hc + h];
  else if (t >= 64 && t < 125)  byh[t - 64]  = by[(t - 64) * Hc + h];
  else if (t >= 128 && t < 149) bzh[t - 128] = bz[(t - 128) * Hc + h];
  // write tile 0 into buffer 0
  *(bf16x8*)((char*)Kb[0] + swzb(row, c0))     = pack8(ka0, ka1);
  *(bf16x8*)((char*)Kb[0] + swzb(row, c0 + 8)) = pack8(ka2, ka3);
  {
    float tv[16];
    *(float4*)(tv)      = va0; *(float4*)(tv + 4)  = va1;
    *(float4*)(tv + 8)  = va2; *(float4*)(tv + 12) = va3;
    #pragma unroll
    for (int i = 0; i < 16; ++i) Vt[0][(c0 + i) * 72 + row] = f2bf(tv[i]);
  }
  if (t < 64)       kxs[0][t]       = rp;
  else if (t < 128) kys[0][t - 64]  = rp;
  else if (t < 192) kzs[0][t - 128] = rp;
  __syncthreads();

  // Q fragments + per-row q positions stay in registers for the whole K loop
  bf16x8 aq[2];
  aq[0] = *(const bf16x8*)((const char*)Qs + swzb(16 * w + lr, 8 * lg));
  aq[1] = *(const bf16x8*)((const char*)Qs + swzb(16 * w + lr, 8 * lg + 32));

  int rowg[4], qxv[4], qyv[4], qzv[4];
  #pragma unroll
  for (int r = 0; r < 4; ++r) {
    const int rl = 16 * w + 4 * lg + r;
    rowg[r] = q0 + rl;
    qxv[r] = qxs[rl]; qyv[r] = qys[rl]; qzv[r] = qzs[rl];
  }

  float mrow[4], lsum[4];
  f32x4 O[4];
  const f32x4 zero4 = {0.f, 0.f, 0.f, 0.f};
  #pragma unroll
  for (int r = 0; r < 4; ++r) { mrow[r] = -INFINITY; lsum[r] = 0.f; }
  #pragma unroll
  for (int nt = 0; nt < 4; ++nt) O[nt] = zero4;

  for (int kt = 0; kt <= qi; ++kt) {
    const int cur = kt & 1;
    const bool pf = (kt < qi);
    const int k0 = kt * 64;

    // ---- issue next-tile global loads early (hide under this tile's compute)
    if (pf) {
      const int k0n = k0 + 64;
      const float4* kp = (const float4*)(kg + (bhOff + k0n + row) * Dc + c0);
      ka0 = kp[0]; ka1 = kp[1]; ka2 = kp[2]; ka3 = kp[3];
      const float4* vp = (const float4*)(vg + (bhOff + k0n + row) * Dc + c0);
      va0 = vp[0]; va1 = vp[1]; va2 = vp[2]; va3 = vp[3];
      if (t < 64)       rp = px[b * Sc + k0n + t];
      else if (t < 128) rp = py[b * Sc + k0n + (t - 64)];
      else if (t < 192) rp = pz[b * Sc + k0n + (t - 128)];
    }

    // ---- S = Q K^T
    f32x4 s[4];
    #pragma unroll
    for (int ct = 0; ct < 4; ++ct) {
      s[ct] = zero4;
      #pragma unroll
      for (int ks = 0; ks < 2; ++ks) {
        bf16x8 bk = *(const bf16x8*)((const char*)Kb[cur] + swzb(16*ct + lr, 8*lg + 32*ks));
        s[ct] = __builtin_amdgcn_mfma_f32_16x16x32_bf16(aq[ks], bk, s[ct], 0, 0, 0);
      }
    }

    // ---- bias + causal mask (scale already folded into Q)
    const bool diag = (kt == qi);
    #pragma unroll
    for (int ct = 0; ct < 4; ++ct) {
      const int colg = k0 + 16*ct + lr;
      const int kxv = kxs[cur][16*ct + lr], kyv = kys[cur][16*ct + lr], kzv = kzs[cur][16*ct + lr];
      #pragma unroll
      for (int r = 0; r < 4; ++r) {
        float val = s[ct][r];
        int dx = qxv[r] - kxv; dx = dx < -30 ? -30 : (dx > 30 ? 30 : dx);
        int dy = qyv[r] - kyv; dy = dy < -30 ? -30 : (dy > 30 ? 30 : dy);
        int dz = qzv[r] - kzv; dz = dz < -10 ? -10 : (dz > 10 ? 10 : dz);
        val += bxh[dx + 30] + byh[dy + 30] + bzh[dz + 10];
        if (diag && colg > rowg[r]) val = -INFINITY;
        s[ct][r] = val;
      }
    }

    // ---- online softmax
    float rmax[4];
    #pragma unroll
    for (int r = 0; r < 4; ++r)
      rmax[r] = fmaxf(fmaxf(s[0][r], s[1][r]), fmaxf(s[2][r], s[3][r]));
    #pragma unroll
    for (int mask = 1; mask <= 8; mask <<= 1) {
      #pragma unroll
      for (int r = 0; r < 4; ++r)
        rmax[r] = fmaxf(rmax[r], __shfl_xor(rmax[r], mask));
    }
    float alpha[4], psum[4];
    #pragma unroll
    for (int r = 0; r < 4; ++r) {
      const float mn = fmaxf(mrow[r], rmax[r]);
      alpha[r] = __expf(mrow[r] - mn);
      mrow[r] = mn;
      psum[r] = 0.f;
    }
    #pragma unroll
    for (int ct = 0; ct < 4; ++ct) {
      #pragma unroll
      for (int r = 0; r < 4; ++r) {
        const float p = __expf(s[ct][r] - mrow[r]);
        s[ct][r] = p;
        psum[r] += p;
      }
    }
    #pragma unroll
    for (int mask = 1; mask <= 8; mask <<= 1) {
      #pragma unroll
      for (int r = 0; r < 4; ++r)
        psum[r] += __shfl_xor(psum[r], mask);
    }
    #pragma unroll
    for (int r = 0; r < 4; ++r) lsum[r] = lsum[r] * alpha[r] + psum[r];
    #pragma unroll
    for (int nt = 0; nt < 4; ++nt) {
      #pragma unroll
      for (int r = 0; r < 4; ++r) O[nt][r] *= alpha[r];
    }

    // ---- P -> bf16 -> LDS (wave-private rows; in-wave LDS ordering suffices)
    #pragma unroll
    for (int ct = 0; ct < 4; ++ct) {
      #pragma unroll
      for (int r = 0; r < 4; ++r)
        *(unsigned short*)((char*)Ps + swzb(16*w + 4*lg + r, 16*ct + lr)) = f2bf(s[ct][r]);
    }
    bf16x8 pa[2];
    pa[0] = *(const bf16x8*)((const char*)Ps + swzb(16*w + lr, 8*lg));
    pa[1] = *(const bf16x8*)((const char*)Ps + swzb(16*w + lr, 8*lg + 32));

    // ---- O += P V : B-frag = Vt rows (d-major, pitch 72), contiguous b128
    #pragma unroll
    for (int nt = 0; nt < 4; ++nt) {
      #pragma unroll
      for (int ks = 0; ks < 2; ++ks) {
        bf16x8 bv = *(const bf16x8*)((const unsigned short*)Vt[cur] + (16*nt + lr) * 72 + 8*lg + 32*ks);
        O[nt] = __builtin_amdgcn_mfma_f32_16x16x32_bf16(pa[ks], bv, O[nt], 0, 0, 0);
      }
    }

    // ---- write next tile into the other buffer (readers of it are one
    // barrier behind; reads of THIS buffer happen before this point).
    if (pf) {
      const int nb = cur ^ 1;
      *(bf16x8*)((char*)Kb[nb] + swzb(row, c0))     = pack8(ka0, ka1);
      *(bf16x8*)((char*)Kb[nb] + swzb(row, c0 + 8)) = pack8(ka2, ka3);
      float tv[16];
      *(float4*)(tv)      = va0; *(float4*)(tv + 4)  = va1;
      *(float4*)(tv + 8)  = va2; *(float4*)(tv + 12) = va3;
      #pragma unroll
      for (int i = 0; i < 16; ++i) Vt[nb][(c0 + i) * 72 + row] = f2bf(tv[i]);
      if (t < 64)       kxs[nb][t]       = rp;
      else if (t < 128) kys[nb][t - 64]  = rp;
      else if (t < 192) kzs[nb][t - 128] = rp;
    }
    __syncthreads();   // single barrier per K-step
  }

  // ---- epilogue: normalize, store fp32
  #pragma unroll
  for (int r = 0; r < 4; ++r) {
    const float inv = 1.0f / lsum[r];
    #pragma unroll
    for (int nt = 0; nt < 4; ++nt)
      outg[(bhOff + q0 + 16*w + 4*lg + r) * Dc + 16*nt + lr] = O[nt][r] * inv;
  }
}

extern "C" void kernel_launch(void* const* d_in, const int* in_sizes, int n_in,
                              void* d_out, int out_size, void* d_ws, size_t ws_size,
                              hipStream_t stream) {
  const float* q  = (const float*)d_in[0];
  const float* k  = (const float*)d_in[1];
  const float* v  = (const float*)d_in[2];
  const int*   px = (const int*)d_in[3];
  const int*   py = (const int*)d_in[4];
  const int*   pz = (const int*)d_in[5];
  const float* bx = (const float*)d_in[6];
  const float* by = (const float*)d_in[7];
  const float* bz = (const float*)d_in[8];
  float* out = (float*)d_out;

  const int grid = (Sc / 64) * Bc * Hc;   // 512 blocks
  attn_rpb_mfma3<<<grid, NTHREADS, 0, stream>>>(q, k, v, px, py, pz, bx, by, bz, out);
}

// Round 5
// 48.428 us; speedup vs baseline: 7.5024x; 1.0121x over previous
//
#include <hip/hip_runtime.h>
#include <math.h>

// FusedAttentionWithRPB: causal attention + bucketed 3D relative-position bias.
// B=4 H=8 S=1024 D=64, fp32 I/O. MFMA bf16 flash kernel, round 5:
//  - round-4 structure (dbuf, prefetch-early/write-late, 1 barrier/step)
//  - combined BXY[61*61] bias table in LDS: 2 gathers/elem instead of 3
//  - DPP (VALU-pipe) butterfly reductions instead of ds_swizzle shuffles
//  - Vt write-side XOR swizzle: 8-way bank conflict -> 2-way

constexpr int Bc = 4, Hc = 8, Sc = 1024, Dc = 64;
constexpr int NTHREADS = 256;

typedef __attribute__((ext_vector_type(8))) short bf16x8;
typedef __attribute__((ext_vector_type(4))) float f32x4;

__device__ __forceinline__ unsigned short f2bf(float f) {
  union { float f; unsigned u; } x; x.f = f;
  unsigned r = x.u + 0x7FFFu + ((x.u >> 16) & 1u);
  return (unsigned short)(r >> 16);
}

__device__ __forceinline__ bf16x8 pack8(float4 a, float4 b) {
  bf16x8 r;
  r[0] = (short)f2bf(a.x); r[1] = (short)f2bf(a.y);
  r[2] = (short)f2bf(a.z); r[3] = (short)f2bf(a.w);
  r[4] = (short)f2bf(b.x); r[5] = (short)f2bf(b.y);
  r[6] = (short)f2bf(b.z); r[7] = (short)f2bf(b.w);
  return r;
}

__device__ __forceinline__ float4 sc4(float4 a, float s) {
  return make_float4(a.x * s, a.y * s, a.z * s, a.w * s);
}

// swizzled byte offset inside a 64x64 bf16 tile (row pitch 128B)
__device__ __forceinline__ int swzb(int row, int col) {
  return ((row << 7) + (col << 1)) ^ ((row & 7) << 4);
}

// Vt (transposed V, [d][key], 144B rows): XOR d's group bits into the 16B-slot
// bits. Write side (scalar b16 at byte 2*key) goes 8-way -> 2-way conflict;
// read side (b128 at 16lg+64ks) stays 16B-aligned and within the row.
__device__ __forceinline__ int vt_off(int d, int boff) {
  return d * 144 + (boff ^ (((d >> 3) & 7) << 4));
}

// DPP cross-lane (VALU pipe, no LDS): butterfly over 16-lane rows.
template<int C>
__device__ __forceinline__ float dppf(float x) {
  return __int_as_float(__builtin_amdgcn_update_dpp(
      __float_as_int(x), __float_as_int(x), C, 0xF, 0xF, false));
}
__device__ __forceinline__ float red_max16(float x) {
  x = fmaxf(x, dppf<0xB1>(x));    // quad_perm(1,0,3,2) = xor1
  x = fmaxf(x, dppf<0x4E>(x));    // quad_perm(2,3,0,1) = xor2
  x = fmaxf(x, dppf<0x141>(x));   // row_half_mirror == xor4 once quads uniform
  x = fmaxf(x, dppf<0x140>(x));   // row_mirror == xor8 once octets uniform
  return x;
}
__device__ __forceinline__ float red_sum16(float x) {
  x += dppf<0xB1>(x);
  x += dppf<0x4E>(x);
  x += dppf<0x141>(x);
  x += dppf<0x140>(x);
  return x;
}

__global__ __launch_bounds__(NTHREADS) void attn_rpb_mfma4(
    const float* __restrict__ qg, const float* __restrict__ kg, const float* __restrict__ vg,
    const int* __restrict__ px, const int* __restrict__ py, const int* __restrict__ pz,
    const float* __restrict__ bx, const float* __restrict__ by, const float* __restrict__ bz,
    float* __restrict__ outg)
{
  // Balanced causal mapping: blocks j and j+256 get complementary q-tiles.
  const int j   = blockIdx.x;
  const int idx = j & 255;
  const int bh  = idx >> 3;
  const int r3  = idx & 7;
  const int qi  = (j < 256) ? (15 - r3) : r3;
  const int h = bh & 7, b = bh >> 3;

  __shared__ unsigned short Qs[64 * 64];      // bf16, swizzled
  __shared__ unsigned short Kb[2][64 * 64];   // bf16, swizzled, double-buffered
  __shared__ unsigned short Vt[2][64 * 72];   // bf16, [d][key], 144B rows, XOR-swizzled
  __shared__ unsigned short Ps[64 * 64];      // bf16, swizzled (wave-private rows)
  __shared__ float BXY[61 * 61];              // bias_x[i]+bias_y[j] for this head
  __shared__ float bzh[21];
  __shared__ int qxs[64], qys[64], qzs[64];
  __shared__ int kxs[2][64], kys[2][64], kzs[2][64];

  const int t  = threadIdx.x;
  const int w  = t >> 6;          // wave 0..3 -> q rows [16w, 16w+16)
  const int l  = t & 63;
  const int lg = l >> 4;          // lane group 0..3
  const int lr = l & 15;          // lane-in-group 0..15
  const size_t bhOff = (size_t)(b * Hc + h) * Sc;
  const int q0 = qi * 64;
  const int row = t >> 2, c0 = (t & 3) * 16;  // staging assignment

  // ---- prologue: tile-0 K/V/pos -> regs; Q (scaled) + tables -> LDS
  float4 ka0, ka1, ka2, ka3, va0, va1, va2, va3;
  int rp = 0;
  {
    const float4* kp = (const float4*)(kg + (bhOff + row) * Dc + c0);
    ka0 = kp[0]; ka1 = kp[1]; ka2 = kp[2]; ka3 = kp[3];
    const float4* vp = (const float4*)(vg + (bhOff + row) * Dc + c0);
    va0 = vp[0]; va1 = vp[1]; va2 = vp[2]; va3 = vp[3];
    if (t < 64)       rp = px[b * Sc + t];
    else if (t < 128) rp = py[b * Sc + (t - 64)];
    else if (t < 192) rp = pz[b * Sc + (t - 128)];
  }
  {
    const float4* qp = (const float4*)(qg + (bhOff + q0 + row) * Dc + c0);
    float4 a0 = sc4(qp[0], 0.125f), a1 = sc4(qp[1], 0.125f);
    float4 a2 = sc4(qp[2], 0.125f), a3 = sc4(qp[3], 0.125f);
    *(bf16x8*)((char*)Qs + swzb(row, c0))     = pack8(a0, a1);
    *(bf16x8*)((char*)Qs + swzb(row, c0 + 8)) = pack8(a2, a3);
  }
  if (t < 64) { qxs[t] = px[b*Sc + q0 + t]; qys[t] = py[b*Sc + q0 + t]; qzs[t] = pz[b*Sc + q0 + t]; }
  if (t < 21) bzh[t] = bz[t * Hc + h];
  // combined XY bias table for this head (one-time; sources are L2-hot)
  for (int e = t; e < 61 * 61; e += NTHREADS) {
    const int i = e / 61, jj = e - i * 61;
    BXY[e] = bx[i * Hc + h] + by[jj * Hc + h];
  }
  // write tile 0 into buffer 0
  *(bf16x8*)((char*)Kb[0] + swzb(row, c0))     = pack8(ka0, ka1);
  *(bf16x8*)((char*)Kb[0] + swzb(row, c0 + 8)) = pack8(ka2, ka3);
  {
    float tv[16];
    *(float4*)(tv)      = va0; *(float4*)(tv + 4)  = va1;
    *(float4*)(tv + 8)  = va2; *(float4*)(tv + 12) = va3;
    #pragma unroll
    for (int i = 0; i < 16; ++i)
      *(unsigned short*)((char*)Vt[0] + vt_off(c0 + i, 2 * row)) = f2bf(tv[i]);
  }
  if (t < 64)       kxs[0][t]       = rp;
  else if (t < 128) kys[0][t - 64]  = rp;
  else if (t < 192) kzs[0][t - 128] = rp;
  __syncthreads();

  // Q fragments + per-row q positions stay in registers for the whole K loop
  bf16x8 aq[2];
  aq[0] = *(const bf16x8*)((const char*)Qs + swzb(16 * w + lr, 8 * lg));
  aq[1] = *(const bf16x8*)((const char*)Qs + swzb(16 * w + lr, 8 * lg + 32));

  int rowg[4], qxv[4], qyv[4], qzv[4];
  #pragma unroll
  for (int r = 0; r < 4; ++r) {
    const int rl = 16 * w + 4 * lg + r;
    rowg[r] = q0 + rl;
    qxv[r] = qxs[rl]; qyv[r] = qys[rl]; qzv[r] = qzs[rl];
  }

  float mrow[4], lsum[4];
  f32x4 O[4];
  const f32x4 zero4 = {0.f, 0.f, 0.f, 0.f};
  #pragma unroll
  for (int r = 0; r < 4; ++r) { mrow[r] = -INFINITY; lsum[r] = 0.f; }
  #pragma unroll
  for (int nt = 0; nt < 4; ++nt) O[nt] = zero4;

  for (int kt = 0; kt <= qi; ++kt) {
    const int cur = kt & 1;
    const bool pf = (kt < qi);
    const int k0 = kt * 64;

    // ---- issue next-tile global loads early (hide under this tile's compute)
    if (pf) {
      const int k0n = k0 + 64;
      const float4* kp = (const float4*)(kg + (bhOff + k0n + row) * Dc + c0);
      ka0 = kp[0]; ka1 = kp[1]; ka2 = kp[2]; ka3 = kp[3];
      const float4* vp = (const float4*)(vg + (bhOff + k0n + row) * Dc + c0);
      va0 = vp[0]; va1 = vp[1]; va2 = vp[2]; va3 = vp[3];
      if (t < 64)       rp = px[b * Sc + k0n + t];
      else if (t < 128) rp = py[b * Sc + k0n + (t - 64)];
      else if (t < 192) rp = pz[b * Sc + k0n + (t - 128)];
    }

    // ---- S = Q K^T
    f32x4 s[4];
    #pragma unroll
    for (int ct = 0; ct < 4; ++ct) {
      s[ct] = zero4;
      #pragma unroll
      for (int ks = 0; ks < 2; ++ks) {
        bf16x8 bk = *(const bf16x8*)((const char*)Kb[cur] + swzb(16*ct + lr, 8*lg + 32*ks));
        s[ct] = __builtin_amdgcn_mfma_f32_16x16x32_bf16(aq[ks], bk, s[ct], 0, 0, 0);
      }
    }

    // ---- bias + causal mask (scale already folded into Q)
    const bool diag = (kt == qi);
    #pragma unroll
    for (int ct = 0; ct < 4; ++ct) {
      const int colg = k0 + 16*ct + lr;
      const int kxv = kxs[cur][16*ct + lr], kyv = kys[cur][16*ct + lr], kzv = kzs[cur][16*ct + lr];
      #pragma unroll
      for (int r = 0; r < 4; ++r) {
        float val = s[ct][r];
        int dx = qxv[r] - kxv; dx = dx < -30 ? -30 : (dx > 30 ? 30 : dx);
        int dy = qyv[r] - kyv; dy = dy < -30 ? -30 : (dy > 30 ? 30 : dy);
        int dz = qzv[r] - kzv; dz = dz < -10 ? -10 : (dz > 10 ? 10 : dz);
        val += BXY[(dx + 30) * 61 + (dy + 30)] + bzh[dz + 10];
        if (diag && colg > rowg[r]) val = -INFINITY;
        s[ct][r] = val;
      }
    }

    // ---- online softmax (reductions on the VALU pipe via DPP)
    float rmax[4];
    #pragma unroll
    for (int r = 0; r < 4; ++r) {
      rmax[r] = fmaxf(fmaxf(s[0][r], s[1][r]), fmaxf(s[2][r], s[3][r]));
      rmax[r] = red_max16(rmax[r]);
    }
    float alpha[4], psum[4];
    #pragma unroll
    for (int r = 0; r < 4; ++r) {
      const float mn = fmaxf(mrow[r], rmax[r]);
      alpha[r] = __expf(mrow[r] - mn);
      mrow[r] = mn;
    }
    #pragma unroll
    for (int ct = 0; ct < 4; ++ct) {
      #pragma unroll
      for (int r = 0; r < 4; ++r) {
        const float p = __expf(s[ct][r] - mrow[r]);
        s[ct][r] = p;
      }
    }
    #pragma unroll
    for (int r = 0; r < 4; ++r) {
      psum[r] = ((s[0][r] + s[1][r]) + (s[2][r] + s[3][r]));
      psum[r] = red_sum16(psum[r]);
      lsum[r] = lsum[r] * alpha[r] + psum[r];
    }
    #pragma unroll
    for (int nt = 0; nt < 4; ++nt) {
      #pragma unroll
      for (int r = 0; r < 4; ++r) O[nt][r] *= alpha[r];
    }

    // ---- P -> bf16 -> LDS (wave-private rows; in-wave LDS ordering suffices)
    #pragma unroll
    for (int ct = 0; ct < 4; ++ct) {
      #pragma unroll
      for (int r = 0; r < 4; ++r)
        *(unsigned short*)((char*)Ps + swzb(16*w + 4*lg + r, 16*ct + lr)) = f2bf(s[ct][r]);
    }
    bf16x8 pa[2];
    pa[0] = *(const bf16x8*)((const char*)Ps + swzb(16*w + lr, 8*lg));
    pa[1] = *(const bf16x8*)((const char*)Ps + swzb(16*w + lr, 8*lg + 32));

    // ---- O += P V : B-frag = Vt rows (d-major), b128 reads, XOR-swizzled
    #pragma unroll
    for (int nt = 0; nt < 4; ++nt) {
      #pragma unroll
      for (int ks = 0; ks < 2; ++ks) {
        bf16x8 bv = *(const bf16x8*)((const char*)Vt[cur] + vt_off(16*nt + lr, 16*lg + 64*ks));
        O[nt] = __builtin_amdgcn_mfma_f32_16x16x32_bf16(pa[ks], bv, O[nt], 0, 0, 0);
      }
    }

    // ---- write next tile into the other buffer
    if (pf) {
      const int nb = cur ^ 1;
      *(bf16x8*)((char*)Kb[nb] + swzb(row, c0))     = pack8(ka0, ka1);
      *(bf16x8*)((char*)Kb[nb] + swzb(row, c0 + 8)) = pack8(ka2, ka3);
      float tv[16];
      *(float4*)(tv)      = va0; *(float4*)(tv + 4)  = va1;
      *(float4*)(tv + 8)  = va2; *(float4*)(tv + 12) = va3;
      #pragma unroll
      for (int i = 0; i < 16; ++i)
        *(unsigned short*)((char*)Vt[nb] + vt_off(c0 + i, 2 * row)) = f2bf(tv[i]);
      if (t < 64)       kxs[nb][t]       = rp;
      else if (t < 128) kys[nb][t - 64]  = rp;
      else if (t < 192) kzs[nb][t - 128] = rp;
    }
    __syncthreads();   // single barrier per K-step
  }

  // ---- epilogue: normalize, store fp32
  #pragma unroll
  for (int r = 0; r < 4; ++r) {
    const float inv = 1.0f / lsum[r];
    #pragma unroll
    for (int nt = 0; nt < 4; ++nt)
      outg[(bhOff + q0 + 16*w + 4*lg + r) * Dc + 16*nt + lr] = O[nt][r] * inv;
  }
}

extern "C" void kernel_launch(void* const* d_in, const int* in_sizes, int n_in,
                              void* d_out, int out_size, void* d_ws, size_t ws_size,
                              hipStream_t stream) {
  const float* q  = (const float*)d_in[0];
  const float* k  = (const float*)d_in[1];
  const float* v  = (const float*)d_in[2];
  const int*   px = (const int*)d_in[3];
  const int*   py = (const int*)d_in[4];
  const int*   pz = (const int*)d_in[5];
  const float* bx = (const float*)d_in[6];
  const float* by = (const float*)d_in[7];
  const float* bz = (const float*)d_in[8];
  float* out = (float*)d_out;

  const int grid = (Sc / 64) * Bc * Hc;   // 512 blocks
  attn_rpb_mfma4<<<grid, NTHREADS, 0, stream>>>(q, k, v, px, py, pz, bx, by, bz, out);
}

// Round 6
// 47.807 us; speedup vs baseline: 7.5999x; 1.0130x over previous
//
#include <hip/hip_runtime.h>
#include <math.h>

// FusedAttentionWithRPB: causal attention + bucketed 3D relative-position bias.
// B=4 H=8 S=1024 D=64, fp32 I/O. MFMA bf16 flash kernel, round 6:
//  - flash-decoding K-split for qi>=8 -> grid 768 (=3/CU), partials in d_ws,
//    tiny combine kernel merges (m,l,O') pairs
//  - LDS cut to ~54 KB (3 blocks/CU): BXY reverted to 3 small tables
//  - otherwise round-5 structure: dbuf, prefetch-early/write-late, 1 barrier/step,
//    DPP reductions, swizzled K/Vt/Ps tiles

constexpr int Bc = 4, Hc = 8, Sc = 1024, Dc = 64;
constexpr int NTHREADS = 256;
// ws: [bh=32][qi-8=8][half=2][row=64][66]: 64 O' + m + l
constexpr size_t WS_NEED = (size_t)Bc * Hc * 8 * 2 * 64 * 66 * sizeof(float);

typedef __attribute__((ext_vector_type(8))) short bf16x8;
typedef __attribute__((ext_vector_type(4))) float f32x4;

__device__ __forceinline__ unsigned short f2bf(float f) {
  union { float f; unsigned u; } x; x.f = f;
  unsigned r = x.u + 0x7FFFu + ((x.u >> 16) & 1u);
  return (unsigned short)(r >> 16);
}

__device__ __forceinline__ bf16x8 pack8(float4 a, float4 b) {
  bf16x8 r;
  r[0] = (short)f2bf(a.x); r[1] = (short)f2bf(a.y);
  r[2] = (short)f2bf(a.z); r[3] = (short)f2bf(a.w);
  r[4] = (short)f2bf(b.x); r[5] = (short)f2bf(b.y);
  r[6] = (short)f2bf(b.z); r[7] = (short)f2bf(b.w);
  return r;
}

__device__ __forceinline__ float4 sc4(float4 a, float s) {
  return make_float4(a.x * s, a.y * s, a.z * s, a.w * s);
}

// swizzled byte offset inside a 64x64 bf16 tile (row pitch 128B)
__device__ __forceinline__ int swzb(int row, int col) {
  return ((row << 7) + (col << 1)) ^ ((row & 7) << 4);
}

// Vt ([d][key], 144B rows): XOR d's group bits into the 16B-slot bits.
__device__ __forceinline__ int vt_off(int d, int boff) {
  return d * 144 + (boff ^ (((d >> 3) & 7) << 4));
}

// DPP cross-lane (VALU pipe): butterfly over 16-lane rows.
template<int C>
__device__ __forceinline__ float dppf(float x) {
  return __int_as_float(__builtin_amdgcn_update_dpp(
      __float_as_int(x), __float_as_int(x), C, 0xF, 0xF, false));
}
__device__ __forceinline__ float red_max16(float x) {
  x = fmaxf(x, dppf<0xB1>(x));
  x = fmaxf(x, dppf<0x4E>(x));
  x = fmaxf(x, dppf<0x141>(x));
  x = fmaxf(x, dppf<0x140>(x));
  return x;
}
__device__ __forceinline__ float red_sum16(float x) {
  x += dppf<0xB1>(x);
  x += dppf<0x4E>(x);
  x += dppf<0x141>(x);
  x += dppf<0x140>(x);
  return x;
}

__global__ __launch_bounds__(NTHREADS) void attn_rpb_mfma5(
    const float* __restrict__ qg, const float* __restrict__ kg, const float* __restrict__ vg,
    const int* __restrict__ px, const int* __restrict__ py, const int* __restrict__ pz,
    const float* __restrict__ bx, const float* __restrict__ by, const float* __restrict__ bz,
    float* __restrict__ outg, float* __restrict__ ws, int mode)
{
  // ---- work descriptor
  int qi, ktb, kte, half; bool split; int bh;
  {
    const int j = blockIdx.x;
    if (mode == 0) {
      // 512 blocks: balanced complementary pairs (round-4 mapping)
      const int idx = j & 255; bh = idx >> 3; const int r3 = idx & 7;
      qi = (j < 256) ? (15 - r3) : r3;
      ktb = 0; kte = qi + 1; split = false; half = 0;
    } else {
      // 768 blocks: triples {i, i+256, i+512} sum to 17 tile-steps each
      const int member = j >> 8, slot = j & 255;
      bh = slot >> 3; const int tri = slot & 7;
      if (member == 0) { qi = tri; ktb = 0; kte = qi + 1; split = false; half = 0; }
      else {
        qi = 15 - tri;
        const int n = qi + 1, n0 = (n + 1) >> 1;
        split = true;
        if (member == 1) { ktb = 0;  kte = n0; half = 0; }
        else             { ktb = n0; kte = n;  half = 1; }
      }
    }
  }
  const int h = bh & 7, b = bh >> 3;

  __shared__ unsigned short Qs[64 * 64];      // bf16, swizzled
  __shared__ unsigned short Kb[2][64 * 64];   // bf16, swizzled, double-buffered
  __shared__ unsigned short Vt[2][64 * 72];   // bf16, [d][key], XOR-swizzled
  __shared__ unsigned short Ps[64 * 64];      // bf16, swizzled (wave-private rows)
  __shared__ float bxh[61], byh[61], bzh[21];
  __shared__ int qxs[64], qys[64], qzs[64];
  __shared__ int kxs[2][64], kys[2][64], kzs[2][64];

  const int t  = threadIdx.x;
  const int w  = t >> 6;
  const int l  = t & 63;
  const int lg = l >> 4;
  const int lr = l & 15;
  const size_t bhOff = (size_t)bh * Sc;
  const int q0 = qi * 64;
  const int kb0 = ktb * 64;
  const int row = t >> 2, c0 = (t & 3) * 16;

  // ---- prologue: tile-ktb K/V/pos -> regs; Q (scaled) + tables -> LDS
  float4 ka0, ka1, ka2, ka3, va0, va1, va2, va3;
  int rp = 0;
  {
    const float4* kp = (const float4*)(kg + (bhOff + kb0 + row) * Dc + c0);
    ka0 = kp[0]; ka1 = kp[1]; ka2 = kp[2]; ka3 = kp[3];
    const float4* vp = (const float4*)(vg + (bhOff + kb0 + row) * Dc + c0);
    va0 = vp[0]; va1 = vp[1]; va2 = vp[2]; va3 = vp[3];
    if (t < 64)       rp = px[b * Sc + kb0 + t];
    else if (t < 128) rp = py[b * Sc + kb0 + (t - 64)];
    else if (t < 192) rp = pz[b * Sc + kb0 + (t - 128)];
  }
  {
    const float4* qp = (const float4*)(qg + (bhOff + q0 + row) * Dc + c0);
    float4 a0 = sc4(qp[0], 0.125f), a1 = sc4(qp[1], 0.125f);
    float4 a2 = sc4(qp[2], 0.125f), a3 = sc4(qp[3], 0.125f);
    *(bf16x8*)((char*)Qs + swzb(row, c0))     = pack8(a0, a1);
    *(bf16x8*)((char*)Qs + swzb(row, c0 + 8)) = pack8(a2, a3);
  }
  if (t < 64) { qxs[t] = px[b*Sc + q0 + t]; qys[t] = py[b*Sc + q0 + t]; qzs[t] = pz[b*Sc + q0 + t]; }
  if (t < 61)                   bxh[t]       = bx[t * Hc + h];
  else if (t >= 64 && t < 125)  byh[t - 64]  = by[(t - 64) * Hc + h];
  else if (t >= 128 && t < 149) bzh[t - 128] = bz[(t - 128) * Hc + h];
  // write tile ktb into buffer 0
  *(bf16x8*)((char*)Kb[0] + swzb(row, c0))     = pack8(ka0, ka1);
  *(bf16x8*)((char*)Kb[0] + swzb(row, c0 + 8)) = pack8(ka2, ka3);
  {
    float tv[16];
    *(float4*)(tv)      = va0; *(float4*)(tv + 4)  = va1;
    *(float4*)(tv + 8)  = va2; *(float4*)(tv + 12) = va3;
    #pragma unroll
    for (int i = 0; i < 16; ++i)
      *(unsigned short*)((char*)Vt[0] + vt_off(c0 + i, 2 * row)) = f2bf(tv[i]);
  }
  if (t < 64)       kxs[0][t]       = rp;
  else if (t < 128) kys[0][t - 64]  = rp;
  else if (t < 192) kzs[0][t - 128] = rp;
  __syncthreads();

  bf16x8 aq[2];
  aq[0] = *(const bf16x8*)((const char*)Qs + swzb(16 * w + lr, 8 * lg));
  aq[1] = *(const bf16x8*)((const char*)Qs + swzb(16 * w + lr, 8 * lg + 32));

  int rowg[4], qxv[4], qyv[4], qzv[4];
  #pragma unroll
  for (int r = 0; r < 4; ++r) {
    const int rl = 16 * w + 4 * lg + r;
    rowg[r] = q0 + rl;
    qxv[r] = qxs[rl]; qyv[r] = qys[rl]; qzv[r] = qzs[rl];
  }

  float mrow[4], lsum[4];
  f32x4 O[4];
  const f32x4 zero4 = {0.f, 0.f, 0.f, 0.f};
  #pragma unroll
  for (int r = 0; r < 4; ++r) { mrow[r] = -INFINITY; lsum[r] = 0.f; }
  #pragma unroll
  for (int nt = 0; nt < 4; ++nt) O[nt] = zero4;

  for (int kt = ktb; kt < kte; ++kt) {
    const int cur = (kt - ktb) & 1;
    const bool pf = (kt + 1 < kte);
    const int k0 = kt * 64;

    // ---- issue next-tile global loads early
    if (pf) {
      const int k0n = k0 + 64;
      const float4* kp = (const float4*)(kg + (bhOff + k0n + row) * Dc + c0);
      ka0 = kp[0]; ka1 = kp[1]; ka2 = kp[2]; ka3 = kp[3];
      const float4* vp = (const float4*)(vg + (bhOff + k0n + row) * Dc + c0);
      va0 = vp[0]; va1 = vp[1]; va2 = vp[2]; va3 = vp[3];
      if (t < 64)       rp = px[b * Sc + k0n + t];
      else if (t < 128) rp = py[b * Sc + k0n + (t - 64)];
      else if (t < 192) rp = pz[b * Sc + k0n + (t - 128)];
    }

    // ---- S = Q K^T
    f32x4 s[4];
    #pragma unroll
    for (int ct = 0; ct < 4; ++ct) {
      s[ct] = zero4;
      #pragma unroll
      for (int ks = 0; ks < 2; ++ks) {
        bf16x8 bk = *(const bf16x8*)((const char*)Kb[cur] + swzb(16*ct + lr, 8*lg + 32*ks));
        s[ct] = __builtin_amdgcn_mfma_f32_16x16x32_bf16(aq[ks], bk, s[ct], 0, 0, 0);
      }
    }

    // ---- bias + causal mask
    const bool diag = (kt == qi);
    #pragma unroll
    for (int ct = 0; ct < 4; ++ct) {
      const int colg = k0 + 16*ct + lr;
      const int kxv = kxs[cur][16*ct + lr], kyv = kys[cur][16*ct + lr], kzv = kzs[cur][16*ct + lr];
      #pragma unroll
      for (int r = 0; r < 4; ++r) {
        float val = s[ct][r];
        int dx = qxv[r] - kxv; dx = dx < -30 ? -30 : (dx > 30 ? 30 : dx);
        int dy = qyv[r] - kyv; dy = dy < -30 ? -30 : (dy > 30 ? 30 : dy);
        int dz = qzv[r] - kzv; dz = dz < -10 ? -10 : (dz > 10 ? 10 : dz);
        val += bxh[dx + 30] + byh[dy + 30] + bzh[dz + 10];
        if (diag && colg > rowg[r]) val = -INFINITY;
        s[ct][r] = val;
      }
    }

    // ---- online softmax (DPP reductions)
    float rmax[4];
    #pragma unroll
    for (int r = 0; r < 4; ++r) {
      rmax[r] = fmaxf(fmaxf(s[0][r], s[1][r]), fmaxf(s[2][r], s[3][r]));
      rmax[r] = red_max16(rmax[r]);
    }
    float alpha[4], psum[4];
    #pragma unroll
    for (int r = 0; r < 4; ++r) {
      const float mn = fmaxf(mrow[r], rmax[r]);
      alpha[r] = __expf(mrow[r] - mn);
      mrow[r] = mn;
    }
    #pragma unroll
    for (int ct = 0; ct < 4; ++ct) {
      #pragma unroll
      for (int r = 0; r < 4; ++r)
        s[ct][r] = __expf(s[ct][r] - mrow[r]);
    }
    #pragma unroll
    for (int r = 0; r < 4; ++r) {
      psum[r] = ((s[0][r] + s[1][r]) + (s[2][r] + s[3][r]));
      psum[r] = red_sum16(psum[r]);
      lsum[r] = lsum[r] * alpha[r] + psum[r];
    }
    #pragma unroll
    for (int nt = 0; nt < 4; ++nt) {
      #pragma unroll
      for (int r = 0; r < 4; ++r) O[nt][r] *= alpha[r];
    }

    // ---- P -> bf16 -> LDS (wave-private rows)
    #pragma unroll
    for (int ct = 0; ct < 4; ++ct) {
      #pragma unroll
      for (int r = 0; r < 4; ++r)
        *(unsigned short*)((char*)Ps + swzb(16*w + 4*lg + r, 16*ct + lr)) = f2bf(s[ct][r]);
    }
    bf16x8 pa[2];
    pa[0] = *(const bf16x8*)((const char*)Ps + swzb(16*w + lr, 8*lg));
    pa[1] = *(const bf16x8*)((const char*)Ps + swzb(16*w + lr, 8*lg + 32));

    // ---- O += P V
    #pragma unroll
    for (int nt = 0; nt < 4; ++nt) {
      #pragma unroll
      for (int ks = 0; ks < 2; ++ks) {
        bf16x8 bv = *(const bf16x8*)((const char*)Vt[cur] + vt_off(16*nt + lr, 16*lg + 64*ks));
        O[nt] = __builtin_amdgcn_mfma_f32_16x16x32_bf16(pa[ks], bv, O[nt], 0, 0, 0);
      }
    }

    // ---- write next tile into the other buffer
    if (pf) {
      const int nb = cur ^ 1;
      *(bf16x8*)((char*)Kb[nb] + swzb(row, c0))     = pack8(ka0, ka1);
      *(bf16x8*)((char*)Kb[nb] + swzb(row, c0 + 8)) = pack8(ka2, ka3);
      float tv[16];
      *(float4*)(tv)      = va0; *(float4*)(tv + 4)  = va1;
      *(float4*)(tv + 8)  = va2; *(float4*)(tv + 12) = va3;
      #pragma unroll
      for (int i = 0; i < 16; ++i)
        *(unsigned short*)((char*)Vt[nb] + vt_off(c0 + i, 2 * row)) = f2bf(tv[i]);
      if (t < 64)       kxs[nb][t]       = rp;
      else if (t < 128) kys[nb][t - 64]  = rp;
      else if (t < 192) kzs[nb][t - 128] = rp;
    }
    __syncthreads();
  }

  // ---- epilogue
  if (!split) {
    #pragma unroll
    for (int r = 0; r < 4; ++r) {
      const float inv = 1.0f / lsum[r];
      #pragma unroll
      for (int nt = 0; nt < 4; ++nt)
        outg[(bhOff + q0 + 16*w + 4*lg + r) * Dc + 16*nt + lr] = O[nt][r] * inv;
    }
  } else {
    float* base = ws + ((((size_t)bh * 8 + (qi - 8)) * 2 + half) * 64) * 66;
    #pragma unroll
    for (int r = 0; r < 4; ++r) {
      float* rowp = base + (16*w + 4*lg + r) * 66;
      #pragma unroll
      for (int nt = 0; nt < 4; ++nt)
        rowp[16*nt + lr] = O[nt][r];
      if (lr == 0) { rowp[64] = mrow[r]; rowp[65] = lsum[r]; }
    }
  }
}

// merge the two K-halves for q-rows 512..1023 of each (b,h)
__global__ __launch_bounds__(256) void attn_rpb_combine(
    const float* __restrict__ ws, float* __restrict__ outg)
{
  const int t = threadIdx.x;
  const int ridx = blockIdx.x * 4 + (t >> 6);   // 0..16383
  const int d = t & 63;
  const int bh = ridx >> 9;
  const int rl = ridx & 511;
  const float* p0 = ws + (((size_t)(bh * 8) + (rl >> 6)) * 2 + 0) * 64 * 66 + (size_t)(rl & 63) * 66;
  const float* p1 = p0 + 64 * 66;
  const float m0 = p0[64], l0 = p0[65];
  const float m1 = p1[64], l1 = p1[65];
  const float m  = fmaxf(m0, m1);
  const float w0 = __expf(m0 - m), w1 = __expf(m1 - m);
  const float lc = l0 * w0 + l1 * w1;
  const float o  = (p0[d] * w0 + p1[d] * w1) / lc;
  outg[((size_t)bh * Sc + 512 + rl) * Dc + d] = o;
}

extern "C" void kernel_launch(void* const* d_in, const int* in_sizes, int n_in,
                              void* d_out, int out_size, void* d_ws, size_t ws_size,
                              hipStream_t stream) {
  const float* q  = (const float*)d_in[0];
  const float* k  = (const float*)d_in[1];
  const float* v  = (const float*)d_in[2];
  const int*   px = (const int*)d_in[3];
  const int*   py = (const int*)d_in[4];
  const int*   pz = (const int*)d_in[5];
  const float* bx = (const float*)d_in[6];
  const float* by = (const float*)d_in[7];
  const float* bz = (const float*)d_in[8];
  float* out = (float*)d_out;
  float* ws  = (float*)d_ws;

  if (ws_size >= WS_NEED) {
    attn_rpb_mfma5<<<768, NTHREADS, 0, stream>>>(q, k, v, px, py, pz, bx, by, bz, out, ws, 1);
    attn_rpb_combine<<<4096, 256, 0, stream>>>(ws, out);
  } else {
    attn_rpb_mfma5<<<512, NTHREADS, 0, stream>>>(q, k, v, px, py, pz, bx, by, bz, out, ws, 0);
  }
}

// Round 7
// 44.988 us; speedup vs baseline: 8.0760x; 1.0626x over previous
//
#include <hip/hip_runtime.h>
#include <math.h>

// FusedAttentionWithRPB round 7: bias-as-MFMA (one-hot augmented QK^T).
// Pre-pass bakes into d_ws: augmented K rows (K bf16 + x/y bias columns,
// XOR-swizzle pre-applied) and transposed+swizzled V tiles. Main kernel
// stages all tiles with global_load_lds; only the z-bias remains as a
// per-element LDS gather (256-entry BZ2 table). 3 blocks/CU.

constexpr int Bc = 4, Hc = 8, Sc = 1024, Dc = 64;
constexpr int NT = 256;

constexpr size_t KA_BYTES  = (size_t)32 * 1024 * 256;            // 8 MB
constexpr size_t VT_BYTES  = (size_t)32 * 16 * 64 * 128;         // 4 MB
constexpr size_t PART_OFF  = KA_BYTES + VT_BYTES;
constexpr size_t PART_BYTES = (size_t)32 * 8 * 2 * 64 * 66 * sizeof(float);
constexpr size_t WS_SPLIT  = PART_OFF + PART_BYTES;

typedef __attribute__((ext_vector_type(8))) short bf16x8;
typedef __attribute__((ext_vector_type(4))) float f32x4;

__device__ __forceinline__ unsigned short f2bf(float f) {
  union { float f; unsigned u; } x; x.f = f;
  unsigned r = x.u + 0x7FFFu + ((x.u >> 16) & 1u);
  return (unsigned short)(r >> 16);
}
__device__ __forceinline__ bf16x8 pack8(float4 a, float4 b) {
  bf16x8 r;
  r[0] = (short)f2bf(a.x); r[1] = (short)f2bf(a.y);
  r[2] = (short)f2bf(a.z); r[3] = (short)f2bf(a.w);
  r[4] = (short)f2bf(b.x); r[5] = (short)f2bf(b.y);
  r[6] = (short)f2bf(b.z); r[7] = (short)f2bf(b.w);
  return r;
}
__device__ __forceinline__ float4 sc4(float4 a, float s) {
  return make_float4(a.x*s, a.y*s, a.z*s, a.w*s);
}
// swizzled byte offset inside a 64x64 bf16 tile (128B rows) for Qs/Ps
__device__ __forceinline__ int swzb(int row, int col) {
  return ((row << 7) + (col << 1)) ^ ((row & 7) << 4);
}
template<int C>
__device__ __forceinline__ float dppf(float x) {
  return __int_as_float(__builtin_amdgcn_update_dpp(
      __float_as_int(x), __float_as_int(x), C, 0xF, 0xF, false));
}
__device__ __forceinline__ float red_max16(float x) {
  x = fmaxf(x, dppf<0xB1>(x));  x = fmaxf(x, dppf<0x4E>(x));
  x = fmaxf(x, dppf<0x141>(x)); x = fmaxf(x, dppf<0x140>(x));
  return x;
}
__device__ __forceinline__ float red_sum16(float x) {
  x += dppf<0xB1>(x);  x += dppf<0x4E>(x);
  x += dppf<0x141>(x); x += dppf<0x140>(x);
  return x;
}
__device__ __forceinline__ void gl16(const void* g, void* l) {
  __builtin_amdgcn_global_load_lds(
      (const __attribute__((address_space(1))) void*)g,
      (__attribute__((address_space(3))) void*)l, 16, 0, 0);
}

// ---- pre-pass 1: augmented K rows. Row (bh,key) = 16 slots of 16B:
// logical slots 0-7 = K dims (bf16), 8-11 = x-bias cols, 12-15 = y-bias cols;
// physical slot = logical ^ (key & 7)  (the LDS read-side XOR, baked here).
__global__ __launch_bounds__(256) void prep_ka(
    const float* __restrict__ kg, const int* __restrict__ px, const int* __restrict__ py,
    const float* __restrict__ bx, const float* __restrict__ by,
    unsigned short* __restrict__ wsKA)
{
  const int t = threadIdx.x;
  const int g = blockIdx.x * 64 + (t >> 2);   // (bh,key) flat, 0..32767
  const int p = t & 3;
  const int bh = g >> 10, key = g & 1023;
  const int b = bh >> 3, h = bh & 7;
  const float* ksrc = kg + ((size_t)bh * Sc + key) * Dc + p * 16;
  float4 f0 = ((const float4*)ksrc)[0], f1 = ((const float4*)ksrc)[1];
  float4 f2 = ((const float4*)ksrc)[2], f3 = ((const float4*)ksrc)[3];
  unsigned short* rowp = wsKA + (size_t)g * 128;
  const int rx = key & 7;
  *(bf16x8*)(rowp + (((2*p)   ^ rx) << 3)) = pack8(f0, f1);
  *(bf16x8*)(rowp + (((2*p+1) ^ rx) << 3)) = pack8(f2, f3);
  const int kx = px[b * Sc + key], ky = py[b * Sc + key];
  bf16x8 xv, yv;
  #pragma unroll
  for (int m = 0; m < 8; ++m) {
    int ix = 8*p + m - kx; ix = ix < -30 ? -30 : (ix > 30 ? 30 : ix);
    int iy = 8*p + m - ky; iy = iy < -30 ? -30 : (iy > 30 ? 30 : iy);
    xv[m] = (short)f2bf(bx[(ix + 30) * Hc + h]);
    yv[m] = (short)f2bf(by[(iy + 30) * Hc + h]);
  }
  *(bf16x8*)(rowp + (((8  + p) ^ rx) << 3)) = xv;
  *(bf16x8*)(rowp + (((12 + p) ^ rx) << 3)) = yv;
}

// ---- pre-pass 2: transposed V tiles. Row (bh,tile,d) = 8 slots of 16B:
// logical slot s = keys [8s,8s+8); physical = s ^ (d & 7).
__global__ __launch_bounds__(256) void prep_vt(
    const float* __restrict__ vg, unsigned short* __restrict__ wsVt)
{
  const int bid = blockIdx.x;              // 512 = 32 bh x 16 tiles
  const int bh = bid >> 4, tt = bid & 15;
  const int t = threadIdx.x;
  const int d = t & 63, cg = t >> 6;       // cg: chunk group 0..3
  unsigned short* rowp = wsVt + (((size_t)bh * 16 + tt) * 64 + d) * 64;
  const float* vbase = vg + ((size_t)bh * Sc + tt * 64) * Dc + d;
  #pragma unroll
  for (int cc = 0; cc < 2; ++cc) {
    const int c = 2 * cg + cc;
    bf16x8 vv;
    #pragma unroll
    for (int j = 0; j < 8; ++j)
      vv[j] = (short)f2bf(vbase[(8*c + j) * Dc]);
    *(bf16x8*)(rowp + ((c ^ (d & 7)) << 3)) = vv;
  }
}

// ---- main kernel
__global__ __launch_bounds__(NT, 3) void attn_rpb_mfma6(
    const float* __restrict__ qg,
    const int* __restrict__ px, const int* __restrict__ py, const int* __restrict__ pz,
    const float* __restrict__ bz,
    const unsigned short* __restrict__ wsKA, const unsigned short* __restrict__ wsVt,
    float* __restrict__ outg, float* __restrict__ wsPart, int mode)
{
  int qi, ktb, kte, half; bool split; int bh;
  {
    const int j = blockIdx.x;
    if (mode == 0) {
      const int idx = j & 255; bh = idx >> 3; const int r3 = idx & 7;
      qi = (j < 256) ? (15 - r3) : r3;
      ktb = 0; kte = qi + 1; split = false; half = 0;
    } else {
      const int member = j >> 8, slot = j & 255;
      bh = slot >> 3; const int tri = slot & 7;
      if (member == 0) { qi = tri; ktb = 0; kte = qi + 1; split = false; half = 0; }
      else {
        qi = 15 - tri;
        const int n = qi + 1, n0 = (n + 1) >> 1;
        split = true;
        if (member == 1) { ktb = 0;  kte = n0; half = 0; }
        else             { ktb = n0; kte = n;  half = 1; }
      }
    }
  }
  const int h = bh & 7, b = bh >> 3;

  __shared__ unsigned short QsPs[64 * 64];   // Q (prologue) then P (loop)
  __shared__ unsigned short KAb[2][64 * 128];
  __shared__ unsigned short Vs[64 * 64];
  __shared__ float BZ2[256];
  __shared__ int qxs[64], qys[64], qzs[64];
  __shared__ int kzs[2][64];

  const int t  = threadIdx.x;
  const int w  = t >> 6;
  const int l  = t & 63;
  const int lg = l >> 4;
  const int lr = l & 15;
  const size_t bhOff = (size_t)bh * Sc;
  const int q0 = qi * 64;
  const int row = t >> 2, c0 = (t & 3) * 16;

  const char* kaSrc = (const char*)wsKA;
  const char* vtSrc = (const char*)wsVt;

  // ---- prologue
  {
    const float4* qp = (const float4*)(qg + (bhOff + q0 + row) * Dc + c0);
    float4 a0 = sc4(qp[0], 0.125f), a1 = sc4(qp[1], 0.125f);
    float4 a2 = sc4(qp[2], 0.125f), a3 = sc4(qp[3], 0.125f);
    *(bf16x8*)((char*)QsPs + swzb(row, c0))     = pack8(a0, a1);
    *(bf16x8*)((char*)QsPs + swzb(row, c0 + 8)) = pack8(a2, a3);
  }
  if (t < 64) {
    qxs[t] = px[b*Sc + q0 + t]; qys[t] = py[b*Sc + q0 + t]; qzs[t] = pz[b*Sc + q0 + t];
    kzs[0][t] = pz[b*Sc + ktb*64 + t];
  }
  {
    int dzz = (t >> 4) - (t & 15); dzz = dzz < -10 ? -10 : (dzz > 10 ? 10 : dzz);
    BZ2[t] = bz[(dzz + 10) * Hc + h];
  }
  // stage KA[0] (tile ktb) and Vs (tile ktb) via global_load_lds
  {
    const char* srcK = kaSrc + ((size_t)(bh*1024 + ktb*64)) * 256 + w*4096 + l*16;
    char* dstK = (char*)KAb[0] + w*4096;
    #pragma unroll
    for (int jj = 0; jj < 4; ++jj) gl16(srcK + jj*1024, dstK + jj*1024);
    const char* srcV = vtSrc + ((size_t)(bh*16 + ktb)) * 8192 + w*2048 + l*16;
    char* dstV = (char*)Vs + w*2048;
    #pragma unroll
    for (int jj = 0; jj < 2; ++jj) gl16(srcV + jj*1024, dstV + jj*1024);
  }
  __syncthreads();

  // A-fragments: Q slices (from LDS) + one-hot x/y slices (registers)
  bf16x8 aq[4];
  aq[0] = *(const bf16x8*)((const char*)QsPs + swzb(16*w + lr, 8*lg));
  aq[1] = *(const bf16x8*)((const char*)QsPs + swzb(16*w + lr, 8*lg + 32));
  {
    const int myrow = 16*w + lr;
    const int qxr = qxs[myrow], qyr = qys[myrow];
    const short one = (short)0x3F80;
    #pragma unroll
    for (int m = 0; m < 8; ++m) {
      aq[2][m] = (qxr == 8*lg + m) ? one : (short)0;
      aq[3][m] = (qyr == 8*lg + m) ? one : (short)0;
    }
  }

  int rowg[4], qz16[4];
  #pragma unroll
  for (int r = 0; r < 4; ++r) {
    const int rl = 16*w + 4*lg + r;
    rowg[r] = q0 + rl;
    qz16[r] = qzs[rl] << 4;
  }

  float mrow[4], lsum[4];
  f32x4 O[4];
  const f32x4 zero4 = {0.f, 0.f, 0.f, 0.f};
  #pragma unroll
  for (int r = 0; r < 4; ++r) { mrow[r] = -INFINITY; lsum[r] = 0.f; }
  #pragma unroll
  for (int nt_ = 0; nt_ < 4; ++nt_) O[nt_] = zero4;

  for (int kt = ktb; kt < kte; ++kt) {
    const int cur = (kt - ktb) & 1;
    const int nb  = cur ^ 1;
    const bool pf = (kt + 1 < kte);
    const int k0 = kt * 64;

    // V for THIS step (single buffer; prologue staged tile ktb)
    if (kt > ktb) {
      const char* srcV = vtSrc + ((size_t)(bh*16 + kt)) * 8192 + w*2048 + l*16;
      char* dstV = (char*)Vs + w*2048;
      #pragma unroll
      for (int jj = 0; jj < 2; ++jj) gl16(srcV + jj*1024, dstV + jj*1024);
    }
    // KA for NEXT step (double buffer), plus kz prefetch
    int rpz = 0;
    if (pf) {
      const char* srcK = kaSrc + ((size_t)(bh*1024 + (kt+1)*64)) * 256 + w*4096 + l*16;
      char* dstK = (char*)KAb[nb] + w*4096;
      #pragma unroll
      for (int jj = 0; jj < 4; ++jj) gl16(srcK + jj*1024, dstK + jj*1024);
      if (t < 64) rpz = pz[b*Sc + (kt+1)*64 + t];
    }

    // ---- S = [Q|onehot] x [K|biascols]^T : K=128, 16 MFMA
    f32x4 s[4];
    #pragma unroll
    for (int ct = 0; ct < 4; ++ct) {
      s[ct] = zero4;
      const char* kab = (const char*)KAb[cur] + (16*ct + lr) * 256;
      #pragma unroll
      for (int ks = 0; ks < 4; ++ks) {
        bf16x8 bk = *(const bf16x8*)(kab + ((((4*ks + lg) ^ (lr & 7))) << 4));
        s[ct] = __builtin_amdgcn_mfma_f32_16x16x32_bf16(aq[ks], bk, s[ct], 0, 0, 0);
      }
    }

    // ---- z-bias + causal mask
    const bool diag = (kt == qi);
    #pragma unroll
    for (int ct = 0; ct < 4; ++ct) {
      const int colg = k0 + 16*ct + lr;
      const int kzv = kzs[cur][16*ct + lr];
      #pragma unroll
      for (int r = 0; r < 4; ++r) {
        float val = s[ct][r] + BZ2[qz16[r] | kzv];
        if (diag && colg > rowg[r]) val = -INFINITY;
        s[ct][r] = val;
      }
    }

    // ---- online softmax (DPP reductions)
    float rmax[4];
    #pragma unroll
    for (int r = 0; r < 4; ++r) {
      rmax[r] = fmaxf(fmaxf(s[0][r], s[1][r]), fmaxf(s[2][r], s[3][r]));
      rmax[r] = red_max16(rmax[r]);
    }
    float alpha[4];
    #pragma unroll
    for (int r = 0; r < 4; ++r) {
      const float mn = fmaxf(mrow[r], rmax[r]);
      alpha[r] = __expf(mrow[r] - mn);
      mrow[r] = mn;
    }
    #pragma unroll
    for (int ct = 0; ct < 4; ++ct) {
      #pragma unroll
      for (int r = 0; r < 4; ++r)
        s[ct][r] = __expf(s[ct][r] - mrow[r]);
    }
    #pragma unroll
    for (int r = 0; r < 4; ++r) {
      float ps = (s[0][r] + s[1][r]) + (s[2][r] + s[3][r]);
      ps = red_sum16(ps);
      lsum[r] = lsum[r] * alpha[r] + ps;
    }
    #pragma unroll
    for (int nt_ = 0; nt_ < 4; ++nt_) {
      #pragma unroll
      for (int r = 0; r < 4; ++r) O[nt_][r] *= alpha[r];
    }

    // ---- P -> bf16 -> LDS (wave-private rows), read back A-frags
    #pragma unroll
    for (int ct = 0; ct < 4; ++ct) {
      #pragma unroll
      for (int r = 0; r < 4; ++r)
        *(unsigned short*)((char*)QsPs + swzb(16*w + 4*lg + r, 16*ct + lr)) = f2bf(s[ct][r]);
    }
    bf16x8 pa[2];
    pa[0] = *(const bf16x8*)((const char*)QsPs + swzb(16*w + lr, 8*lg));
    pa[1] = *(const bf16x8*)((const char*)QsPs + swzb(16*w + lr, 8*lg + 32));

    __syncthreads();   // all waves' V (this step) written; drains vmcnt

    // ---- O += P V
    #pragma unroll
    for (int nt_ = 0; nt_ < 4; ++nt_) {
      const char* vb = (const char*)Vs + (16*nt_ + lr) * 128;
      #pragma unroll
      for (int ks = 0; ks < 2; ++ks) {
        bf16x8 bv = *(const bf16x8*)(vb + ((((4*ks + lg) ^ (lr & 7))) << 4));
        O[nt_] = __builtin_amdgcn_mfma_f32_16x16x32_bf16(pa[ks], bv, O[nt_], 0, 0, 0);
      }
    }

    if (pf && t < 64) kzs[nb][t] = rpz;
    __syncthreads();   // end: next KA/kz visible, V reads done
  }

  // ---- epilogue
  if (!split) {
    #pragma unroll
    for (int r = 0; r < 4; ++r) {
      const float inv = 1.0f / lsum[r];
      #pragma unroll
      for (int nt_ = 0; nt_ < 4; ++nt_)
        outg[(bhOff + q0 + 16*w + 4*lg + r) * Dc + 16*nt_ + lr] = O[nt_][r] * inv;
    }
  } else {
    float* base = wsPart + ((((size_t)bh * 8 + (qi - 8)) * 2 + half) * 64) * 66;
    #pragma unroll
    for (int r = 0; r < 4; ++r) {
      float* rowp = base + (16*w + 4*lg + r) * 66;
      #pragma unroll
      for (int nt_ = 0; nt_ < 4; ++nt_)
        rowp[16*nt_ + lr] = O[nt_][r];
      if (lr == 0) { rowp[64] = mrow[r]; rowp[65] = lsum[r]; }
    }
  }
}

__global__ __launch_bounds__(256) void attn_rpb_combine(
    const float* __restrict__ wsPart, float* __restrict__ outg)
{
  const int t = threadIdx.x;
  const int ridx = blockIdx.x * 4 + (t >> 6);
  const int d = t & 63;
  const int bh = ridx >> 9;
  const int rl = ridx & 511;
  const float* p0 = wsPart + (((size_t)(bh * 8) + (rl >> 6)) * 2 + 0) * 64 * 66 + (size_t)(rl & 63) * 66;
  const float* p1 = p0 + 64 * 66;
  const float m0 = p0[64], l0 = p0[65];
  const float m1 = p1[64], l1 = p1[65];
  const float m  = fmaxf(m0, m1);
  const float w0 = __expf(m0 - m), w1 = __expf(m1 - m);
  const float lc = l0 * w0 + l1 * w1;
  outg[((size_t)bh * Sc + 512 + rl) * Dc + d] = (p0[d] * w0 + p1[d] * w1) / lc;
}

extern "C" void kernel_launch(void* const* d_in, const int* in_sizes, int n_in,
                              void* d_out, int out_size, void* d_ws, size_t ws_size,
                              hipStream_t stream) {
  const float* q  = (const float*)d_in[0];
  const float* k  = (const float*)d_in[1];
  const float* v  = (const float*)d_in[2];
  const int*   px = (const int*)d_in[3];
  const int*   py = (const int*)d_in[4];
  const int*   pz = (const int*)d_in[5];
  const float* bx = (const float*)d_in[6];
  const float* by = (const float*)d_in[7];
  const float* bz = (const float*)d_in[8];
  float* out = (float*)d_out;

  unsigned short* wsKA = (unsigned short*)d_ws;
  unsigned short* wsVt = (unsigned short*)((char*)d_ws + KA_BYTES);
  float* wsPart = (float*)((char*)d_ws + PART_OFF);

  prep_ka<<<512, 256, 0, stream>>>(k, px, py, bx, by, wsKA);
  prep_vt<<<512, 256, 0, stream>>>(v, wsVt);

  if (ws_size >= WS_SPLIT) {
    attn_rpb_mfma6<<<768, NT, 0, stream>>>(q, px, py, pz, bz, wsKA, wsVt, out, wsPart, 1);
    attn_rpb_combine<<<4096, 256, 0, stream>>>(wsPart, out);
  } else {
    attn_rpb_mfma6<<<512, NT, 0, stream>>>(q, px, py, pz, bz, wsKA, wsVt, out, wsPart, 0);
  }
}

// Round 8
// 44.040 us; speedup vs baseline: 8.2500x; 1.0215x over previous
//
#include <hip/hip_runtime.h>
#include <math.h>

// FusedAttentionWithRPB round 8: bias-as-MFMA + fine-grained K-chunking.
//  - 1024 chunk-blocks (static LPT table), 4 blocks/CU (LDS ~35 KB, VGPR<=128)
//  - KA single-buffer + T14 reg-staging; V single-buffer via global_load_lds
//  - Q/one-hot fragments straight to registers (no Q LDS)
//  - fused prep kernel (KA rows + transposed V tiles into d_ws)
//  - combine merges 2-3 partials for qi>=4

constexpr int Bc = 4, Hc = 8, Sc = 1024, Dc = 64;
constexpr int NT = 256;

constexpr size_t KA_BYTES   = (size_t)32 * 1024 * 256;            // 8 MB
constexpr size_t VT_BYTES   = (size_t)32 * 16 * 64 * 128;         // 4 MB
constexpr size_t PART_OFF   = KA_BYTES + VT_BYTES;
constexpr size_t PART_BYTES = (size_t)32 * 12 * 3 * 64 * 66 * sizeof(float);
constexpr size_t WS_SPLIT   = PART_OFF + PART_BYTES;

typedef __attribute__((ext_vector_type(8))) short bf16x8;
typedef __attribute__((ext_vector_type(4))) float f32x4;

// chunk tables: cid -> (qi, ktb, kte, part), heavy-first (LPT)
__device__ __constant__ signed char CQI[32] =
  {15,11,11,10,15,15,14,14,14,13,13,12,10, 9, 9, 8,13,12,12, 8, 7, 7, 6, 3, 6, 5, 5, 4, 2, 4, 1, 0};
__device__ __constant__ signed char CKTB[32] =
  {10, 0, 6, 5, 0, 5, 0, 5,10, 4, 9, 8, 0, 0, 5, 4, 0, 0, 4, 0, 0, 4, 3, 0, 0, 0, 3, 2, 0, 0, 0, 0};
__device__ __constant__ signed char CKTE[32] =
  {16, 6,12,11, 5,10, 5,10,15, 9,14,13, 5, 5,10, 9, 4, 4, 8, 4, 4, 8, 7, 4, 3, 3, 6, 5, 3, 2, 2, 1};
__device__ __constant__ signed char CPT[32] =
  { 2, 0, 1, 1, 0, 1, 0, 1, 2, 1, 2, 2, 0, 0, 1, 1, 0, 0, 1, 0, 0, 1, 1, 0, 0, 0, 1, 1, 0, 0, 0, 0};

__device__ __forceinline__ unsigned short f2bf(float f) {
  union { float f; unsigned u; } x; x.f = f;
  unsigned r = x.u + 0x7FFFu + ((x.u >> 16) & 1u);
  return (unsigned short)(r >> 16);
}
__device__ __forceinline__ bf16x8 pack8(float4 a, float4 b) {
  bf16x8 r;
  r[0] = (short)f2bf(a.x); r[1] = (short)f2bf(a.y);
  r[2] = (short)f2bf(a.z); r[3] = (short)f2bf(a.w);
  r[4] = (short)f2bf(b.x); r[5] = (short)f2bf(b.y);
  r[6] = (short)f2bf(b.z); r[7] = (short)f2bf(b.w);
  return r;
}
__device__ __forceinline__ float4 sc4(float4 a, float s) {
  return make_float4(a.x*s, a.y*s, a.z*s, a.w*s);
}
// swizzled byte offset inside a 64x64 bf16 tile (128B rows) for Ps
__device__ __forceinline__ int swzb(int row, int col) {
  return ((row << 7) + (col << 1)) ^ ((row & 7) << 4);
}
template<int C>
__device__ __forceinline__ float dppf(float x) {
  return __int_as_float(__builtin_amdgcn_update_dpp(
      __float_as_int(x), __float_as_int(x), C, 0xF, 0xF, false));
}
__device__ __forceinline__ float red_max16(float x) {
  x = fmaxf(x, dppf<0xB1>(x));  x = fmaxf(x, dppf<0x4E>(x));
  x = fmaxf(x, dppf<0x141>(x)); x = fmaxf(x, dppf<0x140>(x));
  return x;
}
__device__ __forceinline__ float red_sum16(float x) {
  x += dppf<0xB1>(x);  x += dppf<0x4E>(x);
  x += dppf<0x141>(x); x += dppf<0x140>(x);
  return x;
}
__device__ __forceinline__ void gl16(const void* g, void* l) {
  __builtin_amdgcn_global_load_lds(
      (const __attribute__((address_space(1))) void*)g,
      (__attribute__((address_space(3))) void*)l, 16, 0, 0);
}

// ---- fused pre-pass: blocks 0-511 build augmented-K rows, 512-1023 build Vt.
// KA row (bh,key): 16 slots of 16B; logical 0-7 = K dims, 8-11 = x-bias cols,
// 12-15 = y-bias cols; physical slot = logical ^ (key&7).
// Vt row (bh,tile,d): 8 slots of 16B; logical s = keys [8s,8s+8); phys = s^(d&7).
__global__ __launch_bounds__(256) void prep(
    const float* __restrict__ kg, const float* __restrict__ vg,
    const int* __restrict__ px, const int* __restrict__ py,
    const float* __restrict__ bx, const float* __restrict__ by,
    unsigned short* __restrict__ wsKA, unsigned short* __restrict__ wsVt)
{
  const int t = threadIdx.x;
  if (blockIdx.x < 512) {
    const int g = blockIdx.x * 64 + (t >> 2);
    const int p = t & 3;
    const int bh = g >> 10, key = g & 1023;
    const int b = bh >> 3, h = bh & 7;
    const float* ksrc = kg + ((size_t)bh * Sc + key) * Dc + p * 16;
    float4 f0 = ((const float4*)ksrc)[0], f1 = ((const float4*)ksrc)[1];
    float4 f2 = ((const float4*)ksrc)[2], f3 = ((const float4*)ksrc)[3];
    unsigned short* rowp = wsKA + (size_t)g * 128;
    const int rx = key & 7;
    *(bf16x8*)(rowp + (((2*p)   ^ rx) << 3)) = pack8(f0, f1);
    *(bf16x8*)(rowp + (((2*p+1) ^ rx) << 3)) = pack8(f2, f3);
    const int kx = px[b * Sc + key], ky = py[b * Sc + key];
    bf16x8 xv, yv;
    #pragma unroll
    for (int m = 0; m < 8; ++m) {
      int ix = 8*p + m - kx; ix = ix < -30 ? -30 : (ix > 30 ? 30 : ix);
      int iy = 8*p + m - ky; iy = iy < -30 ? -30 : (iy > 30 ? 30 : iy);
      xv[m] = (short)f2bf(bx[(ix + 30) * Hc + h]);
      yv[m] = (short)f2bf(by[(iy + 30) * Hc + h]);
    }
    *(bf16x8*)(rowp + (((8  + p) ^ rx) << 3)) = xv;
    *(bf16x8*)(rowp + (((12 + p) ^ rx) << 3)) = yv;
  } else {
    const int bid = blockIdx.x - 512;
    const int bh = bid >> 4, tt = bid & 15;
    const int d = t & 63, cg = t >> 6;
    unsigned short* rowp = wsVt + (((size_t)bh * 16 + tt) * 64 + d) * 64;
    const float* vbase = vg + ((size_t)bh * Sc + tt * 64) * Dc + d;
    #pragma unroll
    for (int cc = 0; cc < 2; ++cc) {
      const int c = 2 * cg + cc;
      bf16x8 vv;
      #pragma unroll
      for (int jj = 0; jj < 8; ++jj)
        vv[jj] = (short)f2bf(vbase[(8*c + jj) * Dc]);
      *(bf16x8*)(rowp + ((c ^ (d & 7)) << 3)) = vv;
    }
  }
}

// ---- main kernel
__global__ __launch_bounds__(NT, 4) void attn_rpb_mfma7(
    const float* __restrict__ qg,
    const int* __restrict__ px, const int* __restrict__ py, const int* __restrict__ pz,
    const float* __restrict__ bz,
    const unsigned short* __restrict__ wsKA, const unsigned short* __restrict__ wsVt,
    float* __restrict__ outg, float* __restrict__ wsPart, int mode)
{
  int qi, ktb, kte, part, np, bh;
  {
    const int j = blockIdx.x;
    if (mode == 0) {            // fallback: 512 balanced full-causal blocks
      const int idx = j & 255; bh = idx >> 3; const int r3 = idx & 7;
      qi = (j < 256) ? (15 - r3) : r3;
      ktb = 0; kte = qi + 1; part = 0; np = 1;
    } else {                    // 1024 chunk blocks: j = cid*32 + bh
      bh = j & 31;
      const int cid = j >> 5;
      qi = CQI[cid]; ktb = CKTB[cid]; kte = CKTE[cid]; part = CPT[cid];
      np = (qi < 4) ? 1 : ((qi < 12) ? 2 : 3);
    }
  }
  const int h = bh & 7, b = bh >> 3;

  __shared__ unsigned short KAb[64 * 128];   // 16 KB, single buffer
  __shared__ unsigned short Vs[64 * 64];     // 8 KB, single buffer
  __shared__ unsigned short Ps[64 * 64];     // 8 KB
  __shared__ float BZ2[256];
  __shared__ int kzs[64];

  const int t  = threadIdx.x;
  const int w  = t >> 6;
  const int l  = t & 63;
  const int lg = l >> 4;
  const int lr = l & 15;
  const size_t bhOff = (size_t)bh * Sc;
  const int q0 = qi * 64;

  const char* kaSrc = (const char*)wsKA;
  const char* vtSrc = (const char*)wsVt;

  // ---- prologue: KA[ktb] -> LDS via gl16; tables; Q/one-hot frags -> regs
  {
    const char* srcK = kaSrc + ((size_t)(bh*1024 + ktb*64)) * 256 + w*4096 + l*16;
    char* dstK = (char*)KAb + w*4096 + l*16;
    #pragma unroll
    for (int jj = 0; jj < 4; ++jj) gl16(srcK + jj*1024, dstK + jj*1024);
  }
  if (t < 64) kzs[t] = pz[b*Sc + ktb*64 + t];
  {
    int dzz = (t >> 4) - (t & 15); dzz = dzz < -10 ? -10 : (dzz > 10 ? 10 : dzz);
    BZ2[t] = bz[(dzz + 10) * Hc + h];
  }

  const int myrow = q0 + 16*w + lr;
  bf16x8 aq[4];
  {
    const float* qrow = qg + (bhOff + myrow) * Dc;
    #pragma unroll
    for (int ks = 0; ks < 2; ++ks) {
      float4 f0 = *(const float4*)(qrow + 32*ks + 8*lg);
      float4 f1 = *(const float4*)(qrow + 32*ks + 8*lg + 4);
      aq[ks] = pack8(sc4(f0, 0.125f), sc4(f1, 0.125f));
    }
    const int qxr = px[b*Sc + myrow], qyr = py[b*Sc + myrow];
    const short one = (short)0x3F80;
    #pragma unroll
    for (int m = 0; m < 8; ++m) {
      aq[2][m] = (qxr == 8*lg + m) ? one : (short)0;
      aq[3][m] = (qyr == 8*lg + m) ? one : (short)0;
    }
  }
  int rowg[4], qz16[4];
  #pragma unroll
  for (int r = 0; r < 4; ++r) {
    const int rl = 16*w + 4*lg + r;
    rowg[r] = q0 + rl;
    qz16[r] = pz[b*Sc + q0 + rl] << 4;
  }

  float mrow[4], lsum[4];
  f32x4 O[4];
  const f32x4 zero4 = {0.f, 0.f, 0.f, 0.f};
  #pragma unroll
  for (int r = 0; r < 4; ++r) { mrow[r] = -INFINITY; lsum[r] = 0.f; }
  #pragma unroll
  for (int nt_ = 0; nt_ < 4; ++nt_) O[nt_] = zero4;

  __syncthreads();   // KA[ktb], kzs, BZ2 visible

  for (int kt = ktb; kt < kte; ++kt) {
    const bool pf = (kt + 1 < kte);
    const int k0 = kt * 64;

    // A: stage V[kt] via gl16 (read after mid barrier); KA[kt+1] global->regs
    {
      const char* srcV = vtSrc + ((size_t)(bh*16 + kt)) * 8192 + w*2048 + l*16;
      char* dstV = (char*)Vs + w*2048 + l*16;
      gl16(srcV, dstV);
      gl16(srcV + 1024, dstV + 1024);
    }
    float4 kst0, kst1, kst2, kst3;
    int rpz = 0;
    if (pf) {
      const float4* srcK = (const float4*)(kaSrc + ((size_t)(bh*1024 + (kt+1)*64)) * 256 + w*4096 + l*16);
      kst0 = srcK[0]; kst1 = srcK[64]; kst2 = srcK[128]; kst3 = srcK[192];
      if (t < 64) rpz = pz[b*Sc + (kt+1)*64 + t];
    }

    // B: S = [Q|onehot] x KA^T  (K=128, 16 MFMA)
    f32x4 s[4];
    #pragma unroll
    for (int ct = 0; ct < 4; ++ct) {
      s[ct] = zero4;
      const char* kab = (const char*)KAb + (16*ct + lr) * 256;
      #pragma unroll
      for (int ks = 0; ks < 4; ++ks) {
        bf16x8 bk = *(const bf16x8*)(kab + ((((4*ks + lg) ^ (lr & 7))) << 4));
        s[ct] = __builtin_amdgcn_mfma_f32_16x16x32_bf16(aq[ks], bk, s[ct], 0, 0, 0);
      }
    }

    // C: z-bias + causal mask + online softmax
    const bool diag = (kt == qi);
    #pragma unroll
    for (int ct = 0; ct < 4; ++ct) {
      const int colg = k0 + 16*ct + lr;
      const int kzv = kzs[16*ct + lr];
      #pragma unroll
      for (int r = 0; r < 4; ++r) {
        float val = s[ct][r] + BZ2[qz16[r] | kzv];
        if (diag && colg > rowg[r]) val = -INFINITY;
        s[ct][r] = val;
      }
    }
    float rmax[4];
    #pragma unroll
    for (int r = 0; r < 4; ++r) {
      rmax[r] = fmaxf(fmaxf(s[0][r], s[1][r]), fmaxf(s[2][r], s[3][r]));
      rmax[r] = red_max16(rmax[r]);
    }
    float alpha[4];
    #pragma unroll
    for (int r = 0; r < 4; ++r) {
      const float mn = fmaxf(mrow[r], rmax[r]);
      alpha[r] = __expf(mrow[r] - mn);
      mrow[r] = mn;
    }
    #pragma unroll
    for (int ct = 0; ct < 4; ++ct) {
      #pragma unroll
      for (int r = 0; r < 4; ++r)
        s[ct][r] = __expf(s[ct][r] - mrow[r]);
    }
    #pragma unroll
    for (int r = 0; r < 4; ++r) {
      float ps = (s[0][r] + s[1][r]) + (s[2][r] + s[3][r]);
      ps = red_sum16(ps);
      lsum[r] = lsum[r] * alpha[r] + ps;
    }
    #pragma unroll
    for (int nt_ = 0; nt_ < 4; ++nt_) {
      #pragma unroll
      for (int r = 0; r < 4; ++r) O[nt_][r] *= alpha[r];
    }

    // D: P -> bf16 -> Ps (wave-private rows), read back A-frags
    #pragma unroll
    for (int ct = 0; ct < 4; ++ct) {
      #pragma unroll
      for (int r = 0; r < 4; ++r)
        *(unsigned short*)((char*)Ps + swzb(16*w + 4*lg + r, 16*ct + lr)) = f2bf(s[ct][r]);
    }
    bf16x8 pa[2];
    pa[0] = *(const bf16x8*)((const char*)Ps + swzb(16*w + lr, 8*lg));
    pa[1] = *(const bf16x8*)((const char*)Ps + swzb(16*w + lr, 8*lg + 32));

    __syncthreads();   // E: all waves done reading KAb; Vs gl16 drained

    // F: O += P V
    #pragma unroll
    for (int nt_ = 0; nt_ < 4; ++nt_) {
      const char* vb = (const char*)Vs + (16*nt_ + lr) * 128;
      #pragma unroll
      for (int ks = 0; ks < 2; ++ks) {
        bf16x8 bv = *(const bf16x8*)(vb + ((((4*ks + lg) ^ (lr & 7))) << 4));
        O[nt_] = __builtin_amdgcn_mfma_f32_16x16x32_bf16(pa[ks], bv, O[nt_], 0, 0, 0);
      }
    }

    // F': write KA[kt+1] regs -> KAb; kz for next step
    if (pf) {
      char* dstK = (char*)KAb + w*4096 + l*16;
      *(float4*)(dstK)        = kst0;
      *(float4*)(dstK + 1024) = kst1;
      *(float4*)(dstK + 2048) = kst2;
      *(float4*)(dstK + 3072) = kst3;
      if (t < 64) kzs[t] = rpz;
    }
    __syncthreads();   // G: KAb/kzs writes visible; Vs reads done
  }

  // ---- epilogue
  if (np == 1) {
    #pragma unroll
    for (int r = 0; r < 4; ++r) {
      const float inv = 1.0f / lsum[r];
      #pragma unroll
      for (int nt_ = 0; nt_ < 4; ++nt_)
        outg[(bhOff + q0 + 16*w + 4*lg + r) * Dc + 16*nt_ + lr] = O[nt_][r] * inv;
    }
  } else {
    float* base = wsPart + ((((size_t)bh * 12 + (qi - 4)) * 3 + part) * 64) * 66;
    #pragma unroll
    for (int r = 0; r < 4; ++r) {
      float* rowp = base + (16*w + 4*lg + r) * 66;
      #pragma unroll
      for (int nt_ = 0; nt_ < 4; ++nt_)
        rowp[16*nt_ + lr] = O[nt_][r];
      if (lr == 0) { rowp[64] = mrow[r]; rowp[65] = lsum[r]; }
    }
  }
}

// merge 2-3 partials per (bh, qi>=4) row
__global__ __launch_bounds__(256) void attn_rpb_combine(
    const float* __restrict__ wsPart, float* __restrict__ outg)
{
  const int t = threadIdx.x;
  const int ridx = blockIdx.x * 4 + (t >> 6);   // 0..24575
  const int d = t & 63;
  const int bh = ridx / 768;
  const int rem = ridx - bh * 768;
  const int qj = rem >> 6;        // 0..11 -> qi = qj+4
  const int rl = rem & 63;
  const float* p0 = wsPart + (((size_t)bh * 12 + qj) * 3 + 0) * 64 * 66 + (size_t)rl * 66;
  const float* p1 = p0 + 64 * 66;
  const float m0 = p0[64], l0 = p0[65];
  const float m1 = p1[64], l1 = p1[65];
  float m = fmaxf(m0, m1);
  float o, lc;
  if (qj >= 8) {
    const float* p2 = p1 + 64 * 66;
    const float m2 = p2[64], l2 = p2[65];
    m = fmaxf(m, m2);
    const float w0 = __expf(m0 - m), w1 = __expf(m1 - m), w2 = __expf(m2 - m);
    lc = l0 * w0 + l1 * w1 + l2 * w2;
    o  = p0[d] * w0 + p1[d] * w1 + p2[d] * w2;
  } else {
    const float w0 = __expf(m0 - m), w1 = __expf(m1 - m);
    lc = l0 * w0 + l1 * w1;
    o  = p0[d] * w0 + p1[d] * w1;
  }
  outg[((size_t)bh * Sc + (qj + 4) * 64 + rl) * Dc + d] = o / lc;
}

extern "C" void kernel_launch(void* const* d_in, const int* in_sizes, int n_in,
                              void* d_out, int out_size, void* d_ws, size_t ws_size,
                              hipStream_t stream) {
  const float* q  = (const float*)d_in[0];
  const float* k  = (const float*)d_in[1];
  const float* v  = (const float*)d_in[2];
  const int*   px = (const int*)d_in[3];
  const int*   py = (const int*)d_in[4];
  const int*   pz = (const int*)d_in[5];
  const float* bx = (const float*)d_in[6];
  const float* by = (const float*)d_in[7];
  const float* bz = (const float*)d_in[8];
  float* out = (float*)d_out;

  unsigned short* wsKA = (unsigned short*)d_ws;
  unsigned short* wsVt = (unsigned short*)((char*)d_ws + KA_BYTES);
  float* wsPart = (float*)((char*)d_ws + PART_OFF);

  prep<<<1024, 256, 0, stream>>>(k, v, px, py, bx, by, wsKA, wsVt);

  if (ws_size >= WS_SPLIT) {
    attn_rpb_mfma7<<<1024, NT, 0, stream>>>(q, px, py, pz, bz, wsKA, wsVt, out, wsPart, 1);
    attn_rpb_combine<<<6144, 256, 0, stream>>>(wsPart, out);
  } else {
    attn_rpb_mfma7<<<512, NT, 0, stream>>>(q, px, py, pz, bz, wsKA, wsVt, out, wsPart, 0);
  }
}

// Round 9
// 41.984 us; speedup vs baseline: 8.6539x; 1.0490x over previous
//
#include <hip/hip_runtime.h>
#include <math.h>

// FusedAttentionWithRPB round 9: one-barrier main loop.
//  - KA async double-buffer via global_load_lds (wave-uniform dst)
//  - V fragments read global-direct from ws Vt (no LDS staging, no mid barrier)
//  - kz read global-direct per step; Ps stays wave-private LDS
//  - LDS 41KB, 3 blocks/CU, __launch_bounds__(256,3)

constexpr int Bc = 4, Hc = 8, Sc = 1024, Dc = 64;
constexpr int NT = 256;

constexpr size_t KA_BYTES   = (size_t)32 * 1024 * 256;            // 8 MB
constexpr size_t VT_BYTES   = (size_t)32 * 16 * 64 * 128;         // 4 MB
constexpr size_t PART_OFF   = KA_BYTES + VT_BYTES;
constexpr size_t PART_BYTES = (size_t)32 * 12 * 3 * 64 * 66 * sizeof(float);
constexpr size_t WS_SPLIT   = PART_OFF + PART_BYTES;

typedef __attribute__((ext_vector_type(8))) short bf16x8;
typedef __attribute__((ext_vector_type(4))) float f32x4;

// chunk tables: cid -> (qi, ktb, kte, part), heavy-first (LPT)
__device__ __constant__ signed char CQI[32] =
  {15,11,11,10,15,15,14,14,14,13,13,12,10, 9, 9, 8,13,12,12, 8, 7, 7, 6, 3, 6, 5, 5, 4, 2, 4, 1, 0};
__device__ __constant__ signed char CKTB[32] =
  {10, 0, 6, 5, 0, 5, 0, 5,10, 4, 9, 8, 0, 0, 5, 4, 0, 0, 4, 0, 0, 4, 3, 0, 0, 0, 3, 2, 0, 0, 0, 0};
__device__ __constant__ signed char CKTE[32] =
  {16, 6,12,11, 5,10, 5,10,15, 9,14,13, 5, 5,10, 9, 4, 4, 8, 4, 4, 8, 7, 4, 3, 3, 6, 5, 3, 2, 2, 1};
__device__ __constant__ signed char CPT[32] =
  { 2, 0, 1, 1, 0, 1, 0, 1, 2, 1, 2, 2, 0, 0, 1, 1, 0, 0, 1, 0, 0, 1, 1, 0, 0, 0, 1, 1, 0, 0, 0, 0};

__device__ __forceinline__ unsigned short f2bf(float f) {
  union { float f; unsigned u; } x; x.f = f;
  unsigned r = x.u + 0x7FFFu + ((x.u >> 16) & 1u);
  return (unsigned short)(r >> 16);
}
__device__ __forceinline__ bf16x8 pack8(float4 a, float4 b) {
  bf16x8 r;
  r[0] = (short)f2bf(a.x); r[1] = (short)f2bf(a.y);
  r[2] = (short)f2bf(a.z); r[3] = (short)f2bf(a.w);
  r[4] = (short)f2bf(b.x); r[5] = (short)f2bf(b.y);
  r[6] = (short)f2bf(b.z); r[7] = (short)f2bf(b.w);
  return r;
}
__device__ __forceinline__ float4 sc4(float4 a, float s) {
  return make_float4(a.x*s, a.y*s, a.z*s, a.w*s);
}
// swizzled byte offset inside a 64x64 bf16 tile (128B rows) for Ps
__device__ __forceinline__ int swzb(int row, int col) {
  return ((row << 7) + (col << 1)) ^ ((row & 7) << 4);
}
template<int C>
__device__ __forceinline__ float dppf(float x) {
  return __int_as_float(__builtin_amdgcn_update_dpp(
      __float_as_int(x), __float_as_int(x), C, 0xF, 0xF, false));
}
__device__ __forceinline__ float red_max16(float x) {
  x = fmaxf(x, dppf<0xB1>(x));  x = fmaxf(x, dppf<0x4E>(x));
  x = fmaxf(x, dppf<0x141>(x)); x = fmaxf(x, dppf<0x140>(x));
  return x;
}
__device__ __forceinline__ float red_sum16(float x) {
  x += dppf<0xB1>(x);  x += dppf<0x4E>(x);
  x += dppf<0x141>(x); x += dppf<0x140>(x);
  return x;
}
__device__ __forceinline__ void gl16(const void* g, void* l) {
  __builtin_amdgcn_global_load_lds(
      (const __attribute__((address_space(1))) void*)g,
      (__attribute__((address_space(3))) void*)l, 16, 0, 0);
}

// ---- fused pre-pass (unchanged from round 8)
__global__ __launch_bounds__(256) void prep(
    const float* __restrict__ kg, const float* __restrict__ vg,
    const int* __restrict__ px, const int* __restrict__ py,
    const float* __restrict__ bx, const float* __restrict__ by,
    unsigned short* __restrict__ wsKA, unsigned short* __restrict__ wsVt)
{
  const int t = threadIdx.x;
  if (blockIdx.x < 512) {
    const int g = blockIdx.x * 64 + (t >> 2);
    const int p = t & 3;
    const int bh = g >> 10, key = g & 1023;
    const int b = bh >> 3, h = bh & 7;
    const float* ksrc = kg + ((size_t)bh * Sc + key) * Dc + p * 16;
    float4 f0 = ((const float4*)ksrc)[0], f1 = ((const float4*)ksrc)[1];
    float4 f2 = ((const float4*)ksrc)[2], f3 = ((const float4*)ksrc)[3];
    unsigned short* rowp = wsKA + (size_t)g * 128;
    const int rx = key & 7;
    *(bf16x8*)(rowp + (((2*p)   ^ rx) << 3)) = pack8(f0, f1);
    *(bf16x8*)(rowp + (((2*p+1) ^ rx) << 3)) = pack8(f2, f3);
    const int kx = px[b * Sc + key], ky = py[b * Sc + key];
    bf16x8 xv, yv;
    #pragma unroll
    for (int m = 0; m < 8; ++m) {
      int ix = 8*p + m - kx; ix = ix < -30 ? -30 : (ix > 30 ? 30 : ix);
      int iy = 8*p + m - ky; iy = iy < -30 ? -30 : (iy > 30 ? 30 : iy);
      xv[m] = (short)f2bf(bx[(ix + 30) * Hc + h]);
      yv[m] = (short)f2bf(by[(iy + 30) * Hc + h]);
    }
    *(bf16x8*)(rowp + (((8  + p) ^ rx) << 3)) = xv;
    *(bf16x8*)(rowp + (((12 + p) ^ rx) << 3)) = yv;
  } else {
    const int bid = blockIdx.x - 512;
    const int bh = bid >> 4, tt = bid & 15;
    const int d = t & 63, cg = t >> 6;
    unsigned short* rowp = wsVt + (((size_t)bh * 16 + tt) * 64 + d) * 64;
    const float* vbase = vg + ((size_t)bh * Sc + tt * 64) * Dc + d;
    #pragma unroll
    for (int cc = 0; cc < 2; ++cc) {
      const int c = 2 * cg + cc;
      bf16x8 vv;
      #pragma unroll
      for (int jj = 0; jj < 8; ++jj)
        vv[jj] = (short)f2bf(vbase[(8*c + jj) * Dc]);
      *(bf16x8*)(rowp + ((c ^ (d & 7)) << 3)) = vv;
    }
  }
}

// ---- main kernel
__global__ __launch_bounds__(NT, 3) void attn_rpb_mfma8(
    const float* __restrict__ qg,
    const int* __restrict__ px, const int* __restrict__ py, const int* __restrict__ pz,
    const float* __restrict__ bz,
    const unsigned short* __restrict__ wsKA, const unsigned short* __restrict__ wsVt,
    float* __restrict__ outg, float* __restrict__ wsPart, int mode)
{
  int qi, ktb, kte, part, np, bh;
  {
    const int j = blockIdx.x;
    if (mode == 0) {
      const int idx = j & 255; bh = idx >> 3; const int r3 = idx & 7;
      qi = (j < 256) ? (15 - r3) : r3;
      ktb = 0; kte = qi + 1; part = 0; np = 1;
    } else {
      bh = j & 31;
      const int cid = j >> 5;
      qi = CQI[cid]; ktb = CKTB[cid]; kte = CKTE[cid]; part = CPT[cid];
      np = (qi < 4) ? 1 : ((qi < 12) ? 2 : 3);
    }
  }
  const int h = bh & 7, b = bh >> 3;

  __shared__ unsigned short KAb[2][64 * 128];   // 32 KB, async dbuf
  __shared__ unsigned short Ps[64 * 64];        // 8 KB, wave-private rows
  __shared__ float BZ2[256];

  const int t  = threadIdx.x;
  const int w  = t >> 6;
  const int l  = t & 63;
  const int lg = l >> 4;
  const int lr = l & 15;
  const size_t bhOff = (size_t)bh * Sc;
  const int q0 = qi * 64;

  const char* kaSrc = (const char*)wsKA;
  const char* vtSrc = (const char*)wsVt;

  // ---- prologue: async-stage KA[ktb]; tables; Q/one-hot frags -> regs
  {
    const char* srcK = kaSrc + ((size_t)(bh*1024 + ktb*64)) * 256 + w*4096 + l*16;
    char* dstK = (char*)KAb[0] + w*4096;   // wave-uniform base (+lane*16 by HW)
    #pragma unroll
    for (int jj = 0; jj < 4; ++jj) gl16(srcK + jj*1024, dstK + jj*1024);
  }
  {
    int dzz = (t >> 4) - (t & 15); dzz = dzz < -10 ? -10 : (dzz > 10 ? 10 : dzz);
    BZ2[t] = bz[(dzz + 10) * Hc + h];
  }
  const int myrow = q0 + 16*w + lr;
  bf16x8 aq[4];
  {
    const float* qrow = qg + (bhOff + myrow) * Dc;
    #pragma unroll
    for (int ks = 0; ks < 2; ++ks) {
      float4 f0 = *(const float4*)(qrow + 32*ks + 8*lg);
      float4 f1 = *(const float4*)(qrow + 32*ks + 8*lg + 4);
      aq[ks] = pack8(sc4(f0, 0.125f), sc4(f1, 0.125f));
    }
    const int qxr = px[b*Sc + myrow], qyr = py[b*Sc + myrow];
    const short one = (short)0x3F80;
    #pragma unroll
    for (int m = 0; m < 8; ++m) {
      aq[2][m] = (qxr == 8*lg + m) ? one : (short)0;
      aq[3][m] = (qyr == 8*lg + m) ? one : (short)0;
    }
  }
  int rowg[4], qz16[4];
  #pragma unroll
  for (int r = 0; r < 4; ++r) {
    const int rl = 16*w + 4*lg + r;
    rowg[r] = q0 + rl;
    qz16[r] = pz[b*Sc + q0 + rl] << 4;
  }

  float mrow[4], lsum[4];
  f32x4 O[4];
  const f32x4 zero4 = {0.f, 0.f, 0.f, 0.f};
  #pragma unroll
  for (int r = 0; r < 4; ++r) { mrow[r] = -INFINITY; lsum[r] = 0.f; }
  #pragma unroll
  for (int nt_ = 0; nt_ < 4; ++nt_) O[nt_] = zero4;

  __syncthreads();   // KA[ktb] staged (vmcnt drained), BZ2 visible

  for (int kt = ktb; kt < kte; ++kt) {
    const int cur = (kt - ktb) & 1;
    const int nb  = cur ^ 1;
    const bool pf = (kt + 1 < kte);
    const int k0 = kt * 64;

    // ---- early issues: KA[kt+1] async -> other buffer; V frags + kz -> regs
    if (pf) {
      const char* srcK = kaSrc + ((size_t)(bh*1024 + (kt+1)*64)) * 256 + w*4096 + l*16;
      char* dstK = (char*)KAb[nb] + w*4096;
      #pragma unroll
      for (int jj = 0; jj < 4; ++jj) gl16(srcK + jj*1024, dstK + jj*1024);
    }
    bf16x8 vv[8];
    {
      const char* vtile = vtSrc + ((size_t)(bh*16 + kt)) * 8192;
      #pragma unroll
      for (int nt_ = 0; nt_ < 4; ++nt_) {
        #pragma unroll
        for (int ks = 0; ks < 2; ++ks)
          vv[nt_*2 + ks] = *(const bf16x8*)(vtile + (16*nt_ + lr) * 128
                                            + ((((4*ks + lg) ^ (lr & 7))) << 4));
      }
    }
    int kzv[4];
    #pragma unroll
    for (int ct = 0; ct < 4; ++ct) kzv[ct] = pz[b*Sc + k0 + 16*ct + lr];

    // ---- S = [Q|onehot] x KA^T  (K=128, 16 MFMA)
    f32x4 s[4];
    #pragma unroll
    for (int ct = 0; ct < 4; ++ct) {
      s[ct] = zero4;
      const char* kab = (const char*)KAb[cur] + (16*ct + lr) * 256;
      #pragma unroll
      for (int ks = 0; ks < 4; ++ks) {
        bf16x8 bk = *(const bf16x8*)(kab + ((((4*ks + lg) ^ (lr & 7))) << 4));
        s[ct] = __builtin_amdgcn_mfma_f32_16x16x32_bf16(aq[ks], bk, s[ct], 0, 0, 0);
      }
    }

    // ---- z-bias + causal mask + online softmax
    const bool diag = (kt == qi);
    #pragma unroll
    for (int ct = 0; ct < 4; ++ct) {
      const int colg = k0 + 16*ct + lr;
      #pragma unroll
      for (int r = 0; r < 4; ++r) {
        float val = s[ct][r] + BZ2[qz16[r] | kzv[ct]];
        if (diag && colg > rowg[r]) val = -INFINITY;
        s[ct][r] = val;
      }
    }
    float rmax[4];
    #pragma unroll
    for (int r = 0; r < 4; ++r) {
      rmax[r] = fmaxf(fmaxf(s[0][r], s[1][r]), fmaxf(s[2][r], s[3][r]));
      rmax[r] = red_max16(rmax[r]);
    }
    float alpha[4];
    #pragma unroll
    for (int r = 0; r < 4; ++r) {
      const float mn = fmaxf(mrow[r], rmax[r]);
      alpha[r] = __expf(mrow[r] - mn);
      mrow[r] = mn;
    }
    #pragma unroll
    for (int ct = 0; ct < 4; ++ct) {
      #pragma unroll
      for (int r = 0; r < 4; ++r)
        s[ct][r] = __expf(s[ct][r] - mrow[r]);
    }
    #pragma unroll
    for (int r = 0; r < 4; ++r) {
      float ps = (s[0][r] + s[1][r]) + (s[2][r] + s[3][r]);
      ps = red_sum16(ps);
      lsum[r] = lsum[r] * alpha[r] + ps;
    }
    #pragma unroll
    for (int nt_ = 0; nt_ < 4; ++nt_) {
      #pragma unroll
      for (int r = 0; r < 4; ++r) O[nt_][r] *= alpha[r];
    }

    // ---- P -> bf16 -> Ps (wave-private rows; same-wave ordering suffices)
    #pragma unroll
    for (int ct = 0; ct < 4; ++ct) {
      #pragma unroll
      for (int r = 0; r < 4; ++r)
        *(unsigned short*)((char*)Ps + swzb(16*w + 4*lg + r, 16*ct + lr)) = f2bf(s[ct][r]);
    }
    bf16x8 pa[2];
    pa[0] = *(const bf16x8*)((const char*)Ps + swzb(16*w + lr, 8*lg));
    pa[1] = *(const bf16x8*)((const char*)Ps + swzb(16*w + lr, 8*lg + 32));

    // ---- O += P V (V fragments already in regs)
    #pragma unroll
    for (int nt_ = 0; nt_ < 4; ++nt_) {
      #pragma unroll
      for (int ks = 0; ks < 2; ++ks)
        O[nt_] = __builtin_amdgcn_mfma_f32_16x16x32_bf16(pa[ks], vv[nt_*2 + ks], O[nt_], 0, 0, 0);
    }

    __syncthreads();   // one barrier/step: drains KA[nb] gl16, flips buffers
  }

  // ---- epilogue
  if (np == 1) {
    #pragma unroll
    for (int r = 0; r < 4; ++r) {
      const float inv = 1.0f / lsum[r];
      #pragma unroll
      for (int nt_ = 0; nt_ < 4; ++nt_)
        outg[(bhOff + q0 + 16*w + 4*lg + r) * Dc + 16*nt_ + lr] = O[nt_][r] * inv;
    }
  } else {
    float* base = wsPart + ((((size_t)bh * 12 + (qi - 4)) * 3 + part) * 64) * 66;
    #pragma unroll
    for (int r = 0; r < 4; ++r) {
      float* rowp = base + (16*w + 4*lg + r) * 66;
      #pragma unroll
      for (int nt_ = 0; nt_ < 4; ++nt_)
        rowp[16*nt_ + lr] = O[nt_][r];
      if (lr == 0) { rowp[64] = mrow[r]; rowp[65] = lsum[r]; }
    }
  }
}

// merge 2-3 partials per (bh, qi>=4) row
__global__ __launch_bounds__(256) void attn_rpb_combine(
    const float* __restrict__ wsPart, float* __restrict__ outg)
{
  const int t = threadIdx.x;
  const int ridx = blockIdx.x * 4 + (t >> 6);
  const int d = t & 63;
  const int bh = ridx / 768;
  const int rem = ridx - bh * 768;
  const int qj = rem >> 6;
  const int rl = rem & 63;
  const float* p0 = wsPart + (((size_t)bh * 12 + qj) * 3 + 0) * 64 * 66 + (size_t)rl * 66;
  const float* p1 = p0 + 64 * 66;
  const float m0 = p0[64], l0 = p0[65];
  const float m1 = p1[64], l1 = p1[65];
  float m = fmaxf(m0, m1);
  float o, lc;
  if (qj >= 8) {
    const float* p2 = p1 + 64 * 66;
    const float m2 = p2[64], l2 = p2[65];
    m = fmaxf(m, m2);
    const float w0 = __expf(m0 - m), w1 = __expf(m1 - m), w2 = __expf(m2 - m);
    lc = l0 * w0 + l1 * w1 + l2 * w2;
    o  = p0[d] * w0 + p1[d] * w1 + p2[d] * w2;
  } else {
    const float w0 = __expf(m0 - m), w1 = __expf(m1 - m);
    lc = l0 * w0 + l1 * w1;
    o  = p0[d] * w0 + p1[d] * w1;
  }
  outg[((size_t)bh * Sc + (qj + 4) * 64 + rl) * Dc + d] = o / lc;
}

extern "C" void kernel_launch(void* const* d_in, const int* in_sizes, int n_in,
                              void* d_out, int out_size, void* d_ws, size_t ws_size,
                              hipStream_t stream) {
  const float* q  = (const float*)d_in[0];
  const float* k  = (const float*)d_in[1];
  const float* v  = (const float*)d_in[2];
  const int*   px = (const int*)d_in[3];
  const int*   py = (const int*)d_in[4];
  const int*   pz = (const int*)d_in[5];
  const float* bx = (const float*)d_in[6];
  const float* by = (const float*)d_in[7];
  const float* bz = (const float*)d_in[8];
  float* out = (float*)d_out;

  unsigned short* wsKA = (unsigned short*)d_ws;
  unsigned short* wsVt = (unsigned short*)((char*)d_ws + KA_BYTES);
  float* wsPart = (float*)((char*)d_ws + PART_OFF);

  prep<<<1024, 256, 0, stream>>>(k, v, px, py, bx, by, wsKA, wsVt);

  if (ws_size >= WS_SPLIT) {
    attn_rpb_mfma8<<<1024, NT, 0, stream>>>(q, px, py, pz, bz, wsKA, wsVt, out, wsPart, 1);
    attn_rpb_combine<<<6144, 256, 0, stream>>>(wsPart, out);
  } else {
    attn_rpb_mfma8<<<512, NT, 0, stream>>>(q, px, py, pz, bz, wsKA, wsVt, out, wsPart, 0);
  }
}